// Round 1
// baseline (916.882 us; speedup 1.0000x reference)
//
#include <hip/hip_runtime.h>

typedef __attribute__((ext_vector_type(8))) short short8;
typedef __attribute__((ext_vector_type(4))) float floatx4;
typedef __attribute__((ext_vector_type(4))) unsigned short ushort4v;

#define DEV __device__ __forceinline__

constexpr int M_TOT = 6272;   // 8 * 784 output positions

DEV void async_ld16(const void* g, void* l) {
  __builtin_amdgcn_global_load_lds(
      (const __attribute__((address_space(1))) unsigned int*)g,
      (__attribute__((address_space(3))) unsigned int*)l,
      16, 0, 0);
}

DEV unsigned short f2bf(float x) {
  union { float f; unsigned int u; } v; v.f = x;
  unsigned int u = v.u;
  u += 0x7FFFu + ((u >> 16) & 1u);   // round-to-nearest-even
  return (unsigned short)(u >> 16);
}

DEV float bf2f(unsigned short s) {
  union { unsigned int u; float f; } v; v.u = ((unsigned int)s) << 16;
  return v.f;
}

// ---------------------------------------------------------------------------
// Weight transform: conv_w fp32 [O][C][3][3][3] -> bf16 [tap][o][c]  (B^T).
// ---------------------------------------------------------------------------
__global__ void wtrans(const float* __restrict__ w, unsigned short* __restrict__ wt,
                       int total /* = O*C, multiple of 256 */) {
  __shared__ unsigned short l[256 * 27];
  const int tid  = threadIdx.x;
  const int base = blockIdx.x * 256;
  #pragma unroll 1
  for (int j = tid; j < 256 * 27; j += 256)
    l[j] = f2bf(w[(size_t)base * 27 + j]);
  __syncthreads();
  #pragma unroll 1
  for (int tap = 0; tap < 27; ++tap)
    wt[(size_t)tap * total + base + tid] = l[tid * 27 + tap];
}

// ---------------------------------------------------------------------------
// Build P1: videos fp32 [8][1024][14][14] -> P1 bf16 [t=8][s=6][16][16][1024]
// P1[t][s][h+1][w+1][c] = videos[t-5+s][c][h][w] for s in 1..4 (else zero).
// ---------------------------------------------------------------------------
__global__ void build_P1(const float* __restrict__ videos, unsigned short* __restrict__ P1) {
  const int f  = blockIdx.x;
  const int c0 = blockIdx.y * 64;
  const int tid = threadIdx.x;
  __shared__ unsigned short tile[64][196];

  #pragma unroll 1
  for (int it = 0; it < 49; ++it) {       // 49*256 = 64*196 exactly
    int idx = it * 256 + tid;
    int c = idx / 196, r = idx - c * 196;
    tile[c][r] = f2bf(videos[(size_t)(f * 1024 + c0 + c) * 196 + r]);
  }
  __syncthreads();

  const int c   = tid & 63;
  const int hwq = tid >> 6;
  #pragma unroll 1
  for (int s = 1; s <= 4; ++s) {
    int t = f + 5 - s;
    if (t > 7) continue;
    unsigned short* dst = P1 + (size_t)(t * 6 + s) * 256 * 1024 + (size_t)c0;
    #pragma unroll 1
    for (int it = 0; it < 49; ++it) {
      int hw = it * 4 + hwq;
      int h = hw / 14, w = hw - h * 14;
      dst[(size_t)((h + 1) * 16 + (w + 1)) * 1024 + c] = tile[c][hw];
    }
  }
}

// ---------------------------------------------------------------------------
// R6: implicit-GEMM conv rebuilt on the 256x256 8-wave deep-pipelined template
// (T3+T4+T5): BK=64, 128 KiB double-buffered LDS, 4 phases x 16 MFMA per
// K-step with raw s_barrier + per-phase lgkmcnt(0), stage-one-ahead
// global_load_lds with COUNTED vmcnt(8) (never a full drain in steady state),
// s_setprio(1) around each MFMA cluster.
//
// Work balance by construction: every conv1 full block = exactly 9 valid
// taps (27-tap m-tiles -> 3 K-slices, 18 -> 2, 9 -> 1); conv2 full blocks
// 5 or 6 taps (5 K-slices).  Grid <= 256 blocks, 1 block/CU (128 KiB LDS),
// so per-CU work is uniform without any perm balancing.
//
// Tap slices are contiguous valid-tap ranges; skipped taps contributed exact
// 0.0 before, so results are bit-identical.  Unwritten partial slices are
// pre-zeroed by memset.
//
// A: padded input P [8][6][16][16][CIN] bf16;  B: Wt [27][COUT][CIN] bf16.
// sched entry: x2:5 | n:2 | z:3 | tap0:5 | tap1:5 | tail:1
// ---------------------------------------------------------------------------
template <int COUT, bool TCOND>
__global__ __launch_bounds__(512, 2) void conv_gemm(
    const unsigned short* __restrict__ P,
    const unsigned short* __restrict__ Wt,
    const unsigned int* __restrict__ sched,
    unsigned short* __restrict__ part)
{
  constexpr int CIN = 1024;
  __shared__ short lA[2][256 * 64];   // 2 x 32 KiB
  __shared__ short lB[2][256 * 64];   // 2 x 32 KiB
  const int tid  = threadIdx.x;
  const int wave = tid >> 6;
  const int lane = tid & 63;

  const unsigned int e = sched[blockIdx.x];
  const int x2   = e & 31;
  const int nidx = (e >> 5) & 3;
  const int zs   = (e >> 7) & 7;
  const int tap0 = (e >> 10) & 31;
  const int tap1 = (e >> 15) & 31;
  const int tail = (e >> 20) & 1;
  const int mrows = tail ? 128 : 256;
  const int m0 = x2 * 256;
  const int n0 = nidx * 256;
  unsigned short* partOut = part + (size_t)zs * M_TOT * COUT;

  // Tile-level depth-tap validity over the spanned (t,d) cells.
  bool kdv[3] = {false, false, false};
  {
    const int cA = m0 / 196, cB = (m0 + mrows - 1) / 196;
    for (int c = cA; c <= cB; ++c) {
      int t = c >> 2, d = c & 3;
      #pragma unroll
      for (int kd = 0; kd < 3; ++kd) {
        int s = d + kd;
        bool ok = (s >= 1) && (s <= 4);
        if (TCOND) ok = ok && (s >= 5 - t);
        kdv[kd] = kdv[kd] || ok;
      }
    }
  }

  // Staging geometry: LDS segment s_i = i*512+tid (16B units), row r = s>>3.
  // XOR swizzle: fetch global segment (tid&7)^(r&7)  (involution; read side
  // applies the same XOR so ds_read_b128 is bank-conflict-free).
  const int rb   = tid >> 3;                      // 0..63
  const int segb = (((tid & 7) ^ (rb & 7)) * 16); // byte offset within row
  int aoff[4], boff[4];
  #pragma unroll
  for (int i = 0; i < 4; ++i) {
    int r = i * 64 + rb;
    int m = m0 + r;                 // i>=2 unused for tail blocks
    int t = m / 784;  int r2 = m - t * 784;
    int d = r2 / 196; int r3 = r2 - d * 196;
    int h = r3 / 14;  int w = r3 - h * 14;
    aoff[i] = ((((t * 6 + d) * 16 + h) * 16 + w) * CIN) * 2 + segb;
    boff[i] = (n0 + r) * CIN * 2 + segb;
  }

  // K-step stream: (tap, c0) pairs over valid taps in [tap0, tap1).
  int nvt = 0;
  for (int tp = tap0; tp < tap1; ++tp) if (kdv[tp / 9]) ++nvt;
  const int steps = nvt * (CIN / 64);
  if (steps == 0) return;           // block-uniform; not scheduled in practice
  int tap_s = tap0;
  while (!kdv[tap_s / 9]) ++tap_s;
  int c_s = 0;

  const char* Pb = (const char*)P;
  const char* Wb = (const char*)Wt;

  auto STAGE = [&](int buf) {
    const int kd = tap_s / 9, rm = tap_s - kd * 9;
    const int kh = rm / 3, kw = rm - kh * 3;
    const int tA = (((kd * 16) + kh) * 16 + kw) * (CIN * 2);
    const int tB = tap_s * (COUT * CIN * 2);
    const int cb = c_s * 2;
    async_ld16(Pb + (aoff[0] + tA + cb), (char*)lA[buf] + (size_t)tid * 16);
    async_ld16(Pb + (aoff[1] + tA + cb), (char*)lA[buf] + (size_t)(512 + tid) * 16);
    if (!tail) {
      async_ld16(Pb + (aoff[2] + tA + cb), (char*)lA[buf] + (size_t)(1024 + tid) * 16);
      async_ld16(Pb + (aoff[3] + tA + cb), (char*)lA[buf] + (size_t)(1536 + tid) * 16);
    }
    #pragma unroll
    for (int i = 0; i < 4; ++i)
      async_ld16(Wb + (boff[i] + tB + cb), (char*)lB[buf] + (size_t)(i * 512 + tid) * 16);
    c_s += 64;
    if (c_s == CIN) {
      c_s = 0;
      do { ++tap_s; } while (tap_s < tap1 && !kdv[tap_s / 9]);
    }
  };

  const int wm   = (wave >> 2) * (mrows >> 1);  // 0/128 (full) or 0/64 (tail)
  const int wn   = (wave & 3) * 64;
  const int quad = lane >> 4;
  const int l15  = lane & 15;
  const int xorv = l15 & 7;

  floatx4 acc[8][4];
  const floatx4 zero4 = {0.f, 0.f, 0.f, 0.f};
  #pragma unroll
  for (int i = 0; i < 8; ++i)
    #pragma unroll
    for (int j = 0; j < 4; ++j) acc[i][j] = zero4;

  // Prologue: stage step0 (+step1), wait only step0 (counted), barrier.
  STAGE(0);
  if (steps > 1) {
    STAGE(1);
    if (tail) asm volatile("s_waitcnt vmcnt(6)" ::: "memory");
    else      asm volatile("s_waitcnt vmcnt(8)" ::: "memory");
  } else {
    asm volatile("s_waitcnt vmcnt(0)" ::: "memory");
  }
  __builtin_amdgcn_s_barrier();
  __builtin_amdgcn_sched_barrier(0);

  short8 b[4];
  #pragma unroll 1
  for (int t = 0; t < steps; ++t) {
    const short* A = lA[t & 1];
    const short* B = lB[t & 1];
    // 4 phases: p = (ks<<1)|ihalf ; 16 MFMA per active phase.
    #pragma unroll
    for (int p = 0; p < 4; ++p) {
      const int ks = p >> 1;
      const int ih = p & 1;
      const int sread = ((ks * 4 + quad) ^ xorv) * 8;
      const bool act = (ih == 0) || !tail;   // tail blocks: only 4 i-frags
      short8 a[4];
      if (ih == 0) {
        #pragma unroll
        for (int j = 0; j < 4; ++j)
          b[j] = *(const short8*)(B + (wn + j * 16 + l15) * 64 + sread);
      }
      if (act) {
        #pragma unroll
        for (int i2 = 0; i2 < 4; ++i2)
          a[i2] = *(const short8*)(A + (wm + (ih * 4 + i2) * 16 + l15) * 64 + sread);
      }
      __builtin_amdgcn_s_barrier();
      asm volatile("s_waitcnt lgkmcnt(0)" ::: "memory");
      __builtin_amdgcn_sched_barrier(0);
      __builtin_amdgcn_s_setprio(1);
      if (act) {
        #pragma unroll
        for (int i2 = 0; i2 < 4; ++i2)
          #pragma unroll
          for (int j = 0; j < 4; ++j)
            acc[ih * 4 + i2][j] = __builtin_amdgcn_mfma_f32_16x16x32_bf16(
                a[i2], b[j], acc[ih * 4 + i2][j], 0, 0, 0);
      }
      __builtin_amdgcn_s_setprio(0);
      __builtin_amdgcn_s_barrier();
    }
    // All waves done reading buf[t&1] (per-phase lgkmcnt + trailing barrier).
    __builtin_amdgcn_sched_barrier(0);
    if (t + 2 < steps) {
      STAGE(t & 1);                                     // dest = buf[(t+2)&1]
      // counted wait: step t+1's loads done, step t+2's stay in flight
      if (tail) asm volatile("s_waitcnt vmcnt(6)" ::: "memory");
      else      asm volatile("s_waitcnt vmcnt(8)" ::: "memory");
    } else {
      asm volatile("s_waitcnt vmcnt(0)" ::: "memory");
    }
    __builtin_amdgcn_s_barrier();
    __builtin_amdgcn_sched_barrier(0);
  }

  // Epilogue: C/D layout col=lane&15, row=quad*4+reg. Raw bf16 partials.
  const int im = tail ? 4 : 8;
  #pragma unroll
  for (int i = 0; i < 8; ++i) {
    if (i < im) {
      #pragma unroll
      for (int j = 0; j < 4; ++j) {
        const int o = n0 + wn + j * 16 + l15;
        #pragma unroll
        for (int r = 0; r < 4; ++r) {
          const int m = m0 + wm + i * 16 + quad * 4 + r;
          partOut[(size_t)m * COUT + o] = f2bf(acc[i][j][r]);
        }
      }
    }
  }
}

// ---------------------------------------------------------------------------
// reduce1: sum 3 bf16 partial slices + bias, relu, cast bf16, scatter into
// padded P2 layout [8][6][16][16][1024] (interior only; halo pre-zeroed).
// ---------------------------------------------------------------------------
__global__ void reduce_conv1(const unsigned short* __restrict__ part,
                             const float* __restrict__ bias,
                             unsigned short* __restrict__ P2) {
  const int idx = blockIdx.x * 256 + threadIdx.x;
  const int m  = idx >> 8;
  const int o4 = (idx & 255) * 4;
  const size_t ss = (size_t)M_TOT * 1024;
  const size_t base = (size_t)m * 1024 + o4;
  ushort4v p0 = *(const ushort4v*)(part + base);
  ushort4v p1 = *(const ushort4v*)(part + ss + base);
  ushort4v p2 = *(const ushort4v*)(part + 2 * ss + base);
  ushort4v out;
  #pragma unroll
  for (int k = 0; k < 4; ++k) {
    float v = bf2f(p0[k]) + bf2f(p1[k]) + bf2f(p2[k]) + bias[o4 + k];
    out[k] = f2bf(v > 0.f ? v : 0.f);
  }
  int t = m / 784;  int r2 = m - t * 784;
  int d = r2 / 196; int r3 = r2 - d * 196;
  int h = r3 / 14;  int w = r3 - h * 14;
  size_t didx = (size_t)(((t * 6 + d + 1) * 16 + (h + 1)) * 16 + (w + 1)) * 1024 + o4;
  *(ushort4v*)(P2 + didx) = out;
}

// ---------------------------------------------------------------------------
// reduce2: sum 5 bf16 partial slices + bias, relu, cast bf16 -> h2 [6272][512].
// ---------------------------------------------------------------------------
__global__ void reduce_conv2(const unsigned short* __restrict__ part,
                             const float* __restrict__ bias,
                             unsigned short* __restrict__ h2) {
  const int idx = blockIdx.x * 256 + threadIdx.x;
  const int m  = idx >> 7;
  const int o4 = (idx & 127) * 4;
  const size_t base = (size_t)m * 512 + o4;
  const size_t ss = (size_t)M_TOT * 512;
  float acc[4];
  #pragma unroll
  for (int k = 0; k < 4; ++k) acc[k] = bias[o4 + k];
  #pragma unroll
  for (int s = 0; s < 5; ++s) {
    ushort4v p = *(const ushort4v*)(part + (size_t)s * ss + base);
    #pragma unroll
    for (int k = 0; k < 4; ++k) acc[k] += bf2f(p[k]);
  }
  ushort4v out;
  #pragma unroll
  for (int k = 0; k < 4; ++k) out[k] = f2bf(acc[k] > 0.f ? acc[k] : 0.f);
  *(ushort4v*)(h2 + base) = out;
}

// ---------------------------------------------------------------------------
// Max-pool, two-stage. h2 bf16 >= 0 -> bit pattern monotone -> max raw ushorts.
// ---------------------------------------------------------------------------
__global__ void pool1(const unsigned short* __restrict__ h2,
                      unsigned short* __restrict__ partial) {
  const int t = blockIdx.x / 28, ch = blockIdx.x % 28, o = threadIdx.x;
  const unsigned short* src = h2 + ((size_t)t * 784 + ch * 28) * 512 + o;
  unsigned short m = 0;
  #pragma unroll 4
  for (int i = 0; i < 28; ++i) { unsigned short v = src[(size_t)i * 512]; m = v > m ? v : m; }
  partial[((size_t)t * 28 + ch) * 512 + o] = m;
}

__global__ void pool2(const unsigned short* __restrict__ partial, float* __restrict__ pooled) {
  const int t = blockIdx.x, o = threadIdx.x;
  const unsigned short* src = partial + (size_t)t * 28 * 512 + o;
  unsigned short m = 0;
  #pragma unroll 4
  for (int i = 0; i < 28; ++i) { unsigned short v = src[(size_t)i * 512]; m = v > m ? v : m; }
  pooled[t * 512 + o] = bf2f(m);
}

// ---------------------------------------------------------------------------
// Tiny MLP, fp32. Block per t, 512 threads.
// ---------------------------------------------------------------------------
__global__ void mlp_kernel(const float* __restrict__ pooled,
                           const float* __restrict__ w1, const float* __restrict__ b1,
                           const float* __restrict__ w2, const float* __restrict__ b2,
                           const float* __restrict__ w3, const float* __restrict__ b3,
                           float* __restrict__ out) {
  const int t = blockIdx.x, j = threadIdx.x;
  __shared__ float xa[512], xb[512];
  xa[j] = pooled[t * 512 + j];
  __syncthreads();
  {
    const float4* wr = (const float4*)(w1 + (size_t)j * 512);
    float s = b1[j];
    #pragma unroll 4
    for (int k = 0; k < 128; ++k) {
      float4 wv = wr[k];
      s += wv.x * xa[4*k] + wv.y * xa[4*k+1] + wv.z * xa[4*k+2] + wv.w * xa[4*k+3];
    }
    xb[j] = fmaxf(s, 0.f);
  }
  __syncthreads();
  {
    const float4* wr = (const float4*)(w2 + (size_t)j * 512);
    float s = b2[j];
    #pragma unroll 4
    for (int k = 0; k < 128; ++k) {
      float4 wv = wr[k];
      s += wv.x * xb[4*k] + wv.y * xb[4*k+1] + wv.z * xb[4*k+2] + wv.w * xb[4*k+3];
    }
    xa[j] = fmaxf(s, 0.f);
  }
  __syncthreads();
  if (j < 128) {
    const float4* wr = (const float4*)(w3 + (size_t)j * 512);
    float s = b3[j];
    #pragma unroll 4
    for (int k = 0; k < 128; ++k) {
      float4 wv = wr[k];
      s += wv.x * xa[4*k] + wv.y * xa[4*k+1] + wv.z * xa[4*k+2] + wv.w * xa[4*k+3];
    }
    out[t * 128 + j] = fmaxf(s, 0.f);
  }
}

// ---------------------------------------------------------------------------
// Host-side schedule: per-block (m-tile x2, n-tile, K-slice z, tap range,
// tail flag).  Equal work by construction: conv1 full blocks = exactly 9
// valid taps each (nv/9 slices); conv2 full blocks 5-6 taps (5 slices).
// Grid order g: XCD = g%8 gets a contiguous (n, x2)-sorted chunk (L2 reuse).
// ---------------------------------------------------------------------------
static int build_sched(bool conv1, unsigned int* out) {
  const int nt = conv1 ? 4 : 2;
  unsigned int L[256];
  int cnt = 0;
  for (int n = 0; n < nt; ++n) {
    for (int x2 = 0; x2 < 25; ++x2) {
      const int tail  = (x2 == 24) ? 1 : 0;
      const int mrows = tail ? 128 : 256;
      const int m0 = x2 * 256;
      bool kdv[3] = {false, false, false};
      const int cA = m0 / 196, cB = (m0 + mrows - 1) / 196;
      for (int c = cA; c <= cB; ++c) {
        int t = c >> 2, d = c & 3;
        for (int kd = 0; kd < 3; ++kd) {
          int s = d + kd;
          bool ok = (s >= 1 && s <= 4);
          if (conv1) ok = ok && (s >= 5 - t);
          kdv[kd] = kdv[kd] || ok;
        }
      }
      int vt[27], nv = 0;
      for (int tp = 0; tp < 27; ++tp) if (kdv[tp / 9]) vt[nv++] = tp;
      if (!nv) continue;
      int ns;
      if (conv1) ns = tail ? 2 : nv / 9;   // nv in {9,18,27}
      else       ns = tail ? 2 : 5;
      for (int s = 0; s < ns; ++s) {
        int b0 = nv * s / ns, b1 = nv * (s + 1) / ns;
        int tp0 = vt[b0], tp1 = vt[b1 - 1] + 1;
        L[cnt++] = (unsigned int)(x2 | (n << 5) | (s << 7) | (tp0 << 10) |
                                  (tp1 << 15) | (tail << 20));
      }
    }
  }
  // XCD-grouped interleave: block g -> XCD g%8; XCD b gets L-chunk b.
  const int q = cnt / 8, r = cnt % 8;
  int pos = 0;
  for (int b = 0; b < 8; ++b) {
    const int nb = q + (b < r ? 1 : 0);
    for (int j = 0; j < nb; ++j) out[j * 8 + b] = L[pos++];
  }
  return cnt;
}

// ---------------------------------------------------------------------------
// Workspace layout (bytes) — total 142,215,168 (<= previous 142.46 MB):
//   P12 (P1, later P2)  @ 0          : 25,165,824
//   W1t                 @ 25165824   : 56,623,104   [dead after conv_gemm1]
//     h2   (aliases W1t)@ 25165824   : 6,422,528    [written by reduce_conv2]
//     pooled            @ 31588352   : 16,384
//     ppart             @ 31604736   : 229,376
//   part                @ 81788928   : conv1 3x6272x1024x2 = 38,535,168
//                                      conv2 5x6272x512x2  = 32,112,640
//   W2t                 @ 113901568  : 28,311,552   [written AFTER reduce_conv1
//                                      — overlaps conv1 part slice 3 tail]
//   sched1              @ 142213120  : 1,024
//   sched2              @ 142214144  : 1,024
// ---------------------------------------------------------------------------
extern "C" void kernel_launch(void* const* d_in, const int* in_sizes, int n_in,
                              void* d_out, int out_size, void* d_ws, size_t ws_size,
                              hipStream_t stream) {
  const float* videos = (const float*)d_in[0];
  const float* c1w = (const float*)d_in[1];
  const float* c1b = (const float*)d_in[2];
  const float* c2w = (const float*)d_in[3];
  const float* c2b = (const float*)d_in[4];
  const float* l1w = (const float*)d_in[5];
  const float* l1b = (const float*)d_in[6];
  const float* l2w = (const float*)d_in[7];
  const float* l2b = (const float*)d_in[8];
  const float* l3w = (const float*)d_in[9];
  const float* l3b = (const float*)d_in[10];

  char* ws = (char*)d_ws;
  unsigned short* P12   = (unsigned short*)(ws);
  unsigned short* W1t   = (unsigned short*)(ws + 25165824);
  unsigned short* h2    = (unsigned short*)(ws + 25165824);   // aliases W1t
  float*          pooled= (float*)(ws + 31588352);
  unsigned short* ppart = (unsigned short*)(ws + 31604736);
  unsigned short* part  = (unsigned short*)(ws + 81788928);
  unsigned short* W2t   = (unsigned short*)(ws + 113901568);
  unsigned int* dsched1 = (unsigned int*)(ws + 142213120);
  unsigned int* dsched2 = (unsigned int*)(ws + 142214144);
  float* out = (float*)d_out;

  // Host scheds: static so the captured memcpy source persists across graph
  // replays; recomputed identically every call.
  static unsigned int s1h[256], s2h[256];
  const int n1 = build_sched(true,  s1h);   // 228 blocks
  const int n2 = build_sched(false, s2h);   // 244 blocks
  hipMemcpyAsync(dsched1, s1h, sizeof(s1h), hipMemcpyHostToDevice, stream);
  hipMemcpyAsync(dsched2, s2h, sizeof(s2h), hipMemcpyHostToDevice, stream);

  // Zero padded activation buffer (halo + unused windows must be 0).
  hipMemsetAsync(ws, 0, 25165824, stream);
  // Zero conv1 partials (empty m-tiles + slices unused by 1/2-slice cells).
  hipMemsetAsync(part, 0, 38535168, stream);

  wtrans<<<4096, 256, 0, stream>>>(c1w, W1t, 1024 * 1024);
  build_P1<<<dim3(8, 16), 256, 0, stream>>>(videos, P12);

  conv_gemm<1024, true ><<<n1, 512, 0, stream>>>(P12, W1t, dsched1, part);
  reduce_conv1<<<6272, 256, 0, stream>>>(part, c1b, P12);

  // W2t overlaps conv1 partial slice 3 — must be built after reduce_conv1.
  wtrans<<<2048, 256, 0, stream>>>(c2w, W2t, 512 * 1024);
  // Zero conv2 partial slices 1..4 (slice 0 fully covered).
  hipMemsetAsync((char*)part + 6422528, 0, 25690112, stream);

  conv_gemm<512, false><<<n2, 512, 0, stream>>>(P12, W2t, dsched2, part);
  reduce_conv2<<<3136, 256, 0, stream>>>(part, c2b, h2);

  pool1<<<224, 512, 0, stream>>>(h2, ppart);
  pool2<<<8, 512, 0, stream>>>(ppart, pooled);
  mlp_kernel<<<8, 512, 0, stream>>>(pooled, l1w, l1b, l2w, l2b, l3w, l3b, out);
}

// Round 4
// 815.115 us; speedup vs baseline: 1.1249x; 1.1249x over previous
//
#include <hip/hip_runtime.h>

typedef __attribute__((ext_vector_type(8))) short short8;
typedef __attribute__((ext_vector_type(4))) float floatx4;
typedef __attribute__((ext_vector_type(4))) unsigned short ushort4v;

#define DEV __device__ __forceinline__

constexpr int M_TOT = 6272;   // 8 * 784 real output positions
constexpr int M_PAD = 6400;   // padded to 25*256 (pad rows read zeroed P slots)

DEV void async_ld16(const void* g, void* l) {
  __builtin_amdgcn_global_load_lds(
      (const __attribute__((address_space(1))) unsigned int*)g,
      (__attribute__((address_space(3))) unsigned int*)l,
      16, 0, 0);
}

DEV unsigned short f2bf(float x) {
  union { float f; unsigned int u; } v; v.f = x;
  unsigned int u = v.u;
  u += 0x7FFFu + ((u >> 16) & 1u);   // round-to-nearest-even
  return (unsigned short)(u >> 16);
}

DEV float bf2f(unsigned short s) {
  union { unsigned int u; float f; } v; v.u = ((unsigned int)s) << 16;
  return v.f;
}

// ---------------------------------------------------------------------------
// Weight transform: conv_w fp32 [O][C][3][3][3] -> bf16 [tap][o][c]  (B^T).
// ---------------------------------------------------------------------------
__global__ void wtrans(const float* __restrict__ w, unsigned short* __restrict__ wt,
                       int total /* = O*C, multiple of 256 */) {
  __shared__ unsigned short l[256 * 27];
  const int tid  = threadIdx.x;
  const int base = blockIdx.x * 256;
  #pragma unroll 1
  for (int j = tid; j < 256 * 27; j += 256)
    l[j] = f2bf(w[(size_t)base * 27 + j]);
  __syncthreads();
  #pragma unroll 1
  for (int tap = 0; tap < 27; ++tap)
    wt[(size_t)tap * total + base + tid] = l[tid * 27 + tap];
}

// ---------------------------------------------------------------------------
// Build P1: videos fp32 [8][1024][14][14] -> P1 bf16 [t=8][s=6][16][16][1024]
// P1[t][s][h+1][w+1][c] = videos[t-5+s][c][h][w] for s in 1..4 (else zero).
// ---------------------------------------------------------------------------
__global__ void build_P1(const float* __restrict__ videos, unsigned short* __restrict__ P1) {
  const int f  = blockIdx.x;
  const int c0 = blockIdx.y * 64;
  const int tid = threadIdx.x;
  __shared__ unsigned short tile[64][196];

  #pragma unroll 1
  for (int it = 0; it < 49; ++it) {       // 49*256 = 64*196 exactly
    int idx = it * 256 + tid;
    int c = idx / 196, r = idx - c * 196;
    tile[c][r] = f2bf(videos[(size_t)(f * 1024 + c0 + c) * 196 + r]);
  }
  __syncthreads();

  const int c   = tid & 63;
  const int hwq = tid >> 6;
  #pragma unroll 1
  for (int s = 1; s <= 4; ++s) {
    int t = f + 5 - s;
    if (t > 7) continue;
    unsigned short* dst = P1 + (size_t)(t * 6 + s) * 256 * 1024 + (size_t)c0;
    #pragma unroll 1
    for (int it = 0; it < 49; ++it) {
      int hw = it * 4 + hwq;
      int h = hw / 14, w = hw - h * 14;
      dst[(size_t)((h + 1) * 16 + (w + 1)) * 1024 + c] = tile[c][hw];
    }
  }
}

// ---------------------------------------------------------------------------
// R8 (hardened R7): 256x256 tile, BK=32, QUAD-buffered LDS (4 slots x 32 KiB).
// Step t computes from slot t&3 and stages step t+3 into slot (t+3)&3 ==
// (t-1)&3 (dead since the previous closing barrier) -> staging spreads 2
// loads per phase INSIDE the phases (m196's fine-interleave lever), >= 6
// phases of latency cover per load.  Boundary s_waitcnt vmcnt(8) keeps 8
// loads (steps t+2,t+3) in flight and waits only on loads issued 2 full
// steps earlier.  2 phases x 16 MFMA per step, raw s_barrier pairs,
// setprio(1) around MFMA clusters, sched_barrier(0) after each waitcnt.
//
// Hardening vs R7: prologue clamped to min(steps,3) stages with matching
// counted wait; full vmcnt(0)+lgkmcnt(0) drain + barrier after the main
// loop; b[] fragment array scoped inside the loop.
//
// M padded to 6400: no tail blocks; all conv1 blocks exactly 9 taps (288
// steps) -> perfect per-CU balance at 1 block/CU.  Pad rows read zeroed P
// slots (t=8) -> contribute exact 0; pad part rows never read by reducers.
//
// LDS k-swizzle (64-B rows, 4 segs of 16 B): LDS(row,seg) holds global
// chunk seg ^ ((row>>1)&3); read seg = quad ^ ((l15>>1)&3).  8 consecutive
// lanes of a b128 cover all 32 banks exactly once -> conflict-free.
//
// A: padded input P [t=0..8][6][16][16][1024] bf16; B: Wt [27][COUT][1024].
// sched entry: x2:5 | n:2 | z:3 | tap0:5 | tap1:5
// ---------------------------------------------------------------------------
template <int COUT, bool TCOND>
__global__ __launch_bounds__(512, 2) void conv_gemm(
    const unsigned short* __restrict__ P,
    const unsigned short* __restrict__ Wt,
    const unsigned int* __restrict__ sched,
    unsigned short* __restrict__ part)
{
  constexpr int CIN = 1024;
  __shared__ short lA[4][8192];   // 4 slots x 16 KiB  (256 rows x 32 k)
  __shared__ short lB[4][8192];
  const int tid  = threadIdx.x;
  const int wave = tid >> 6;
  const int lane = tid & 63;

  const unsigned int e = sched[blockIdx.x];
  const int x2   = e & 31;
  const int nidx = (e >> 5) & 3;
  const int zs   = (e >> 7) & 7;
  const int tap0 = (e >> 10) & 31;
  const int tap1 = (e >> 15) & 31;
  const int m0 = x2 * 256;
  const int n0 = nidx * 256;
  unsigned short* partOut = part + (size_t)zs * M_PAD * COUT;

  // Tile-level depth-tap validity over spanned REAL (t,d) cells (pad excluded).
  bool kdv[3] = {false, false, false};
  {
    const int cA = m0 / 196;
    int cB = (m0 + 255) / 196; if (cB > 31) cB = 31;
    for (int c = cA; c <= cB; ++c) {
      int t = c >> 2, d = c & 3;
      #pragma unroll
      for (int kd = 0; kd < 3; ++kd) {
        int s = d + kd;
        bool ok = (s >= 1) && (s <= 4);
        if (TCOND) ok = ok && (s >= 5 - t);
        kdv[kd] = kdv[kd] || ok;
      }
    }
  }

  // Staging geometry: thread covers (row = tid>>2 within 128-row half,
  // seg = tid&3); global source pre-swizzled: chunk (tid&3) ^ ((row>>1)&3).
  const int arow = tid >> 2;
  const int aswz = (((tid & 3) ^ ((arow >> 1) & 3)) << 4);
  int aG[2], bG[2];
  #pragma unroll
  for (int q = 0; q < 2; ++q) {
    int m = m0 + q * 128 + arow;
    int t = m / 784;  int r2 = m - t * 784;
    int d = r2 / 196; int r3 = r2 - d * 196;
    int h = r3 / 14;  int w = r3 - h * 14;
    aG[q] = ((((t * 6 + d) * 16 + h) * 16 + w) * CIN) * 2 + aswz;
    bG[q] = (n0 + q * 128 + arow) * (CIN * 2) + aswz;
  }

  // Step stream: 32 K-steps per valid tap.
  int nvt = 0;
  for (int tp = tap0; tp < tap1; ++tp) if (kdv[tp / 9]) ++nvt;
  const int steps = nvt * 32;
  int tap_s = tap0;
  while (tap_s < tap1 && !kdv[tap_s / 9]) ++tap_s;
  int c_s = 0;
  int stA = 0, stB = 0;
  auto setBases = [&]() {
    const int kd = tap_s / 9, rm = tap_s - kd * 9;
    const int kh = rm / 3, kw = rm - kh * 3;
    stA = ((((kd * 16) + kh) * 16 + kw) * CIN) * 2 + c_s * 2;
    stB = tap_s * (COUT * CIN * 2) + c_s * 2;
  };
  auto adv = [&]() {
    c_s += 32;
    if (c_s == CIN) { c_s = 0; do { ++tap_s; } while (tap_s < tap1 && !kdv[tap_s / 9]); }
  };

  const char* Pb = (const char*)P;
  const char* Wb = (const char*)Wt;
  char* lAc = (char*)&lA[0][0];
  char* lBc = (char*)&lB[0][0];

  // Prologue: stage steps 0..min(steps,3)-1 into slots 0.., counted wait on
  // step 0 only.
  const int nst = steps < 3 ? steps : 3;
  #pragma unroll 1
  for (int s = 0; s < nst; ++s) {
    setBases();
    char* dA = lAc + s * 16384;
    char* dB = lBc + s * 16384;
    async_ld16(Pb + aG[0] + stA, dA + tid * 16);
    async_ld16(Wb + bG[0] + stB, dB + tid * 16);
    async_ld16(Pb + aG[1] + stA, dA + 8192 + tid * 16);
    async_ld16(Wb + bG[1] + stB, dB + 8192 + tid * 16);
    adv();
  }
  if (nst >= 3)      asm volatile("s_waitcnt vmcnt(8)" ::: "memory");
  else if (nst == 2) asm volatile("s_waitcnt vmcnt(4)" ::: "memory");
  else               asm volatile("s_waitcnt vmcnt(0)" ::: "memory");
  __builtin_amdgcn_s_barrier();
  __builtin_amdgcn_sched_barrier(0);

  const int wm   = (wave >> 2) * 128;
  const int wn   = (wave & 3) * 64;
  const int quad = lane >> 4;
  const int l15  = lane & 15;
  const int segc = ((quad ^ ((l15 >> 1) & 3)) << 4);

  floatx4 acc[8][4];
  const floatx4 zero4 = {0.f, 0.f, 0.f, 0.f};
  #pragma unroll
  for (int i = 0; i < 8; ++i)
    #pragma unroll
    for (int j = 0; j < 4; ++j) acc[i][j] = zero4;

  #pragma unroll 1
  for (int t = 0; t < steps; ++t) {
    const char* Ap = lAc + (t & 3) * 16384;
    const char* Bp = lBc + (t & 3) * 16384;
    const bool h3s = (t + 3 < steps);
    const bool h2s = (t + 2 < steps);
    char* dA = lAc + ((t + 3) & 3) * 16384;
    char* dB = lBc + ((t + 3) & 3) * 16384;
    if (h3s) setBases();

    short8 b[4];
    // ---------------- phase 0: rows wm..wm+63 ----------------
    short8 a0[4];
    #pragma unroll
    for (int j = 0; j < 4; ++j)
      b[j] = *(const short8*)(Bp + ((wn + j * 16 + l15) << 6) + segc);
    #pragma unroll
    for (int i = 0; i < 4; ++i)
      a0[i] = *(const short8*)(Ap + ((wm + i * 16 + l15) << 6) + segc);
    if (h3s) {
      async_ld16(Pb + aG[0] + stA, dA + tid * 16);
      async_ld16(Wb + bG[0] + stB, dB + tid * 16);
    }
    __builtin_amdgcn_s_barrier();
    asm volatile("s_waitcnt lgkmcnt(0)" ::: "memory");
    __builtin_amdgcn_sched_barrier(0);
    __builtin_amdgcn_s_setprio(1);
    #pragma unroll
    for (int i = 0; i < 4; ++i)
      #pragma unroll
      for (int j = 0; j < 4; ++j)
        acc[i][j] = __builtin_amdgcn_mfma_f32_16x16x32_bf16(a0[i], b[j], acc[i][j], 0, 0, 0);
    __builtin_amdgcn_s_setprio(0);
    __builtin_amdgcn_s_barrier();

    // ---------------- phase 1: rows wm+64..wm+127 ----------------
    short8 a1[4];
    #pragma unroll
    for (int i = 0; i < 4; ++i)
      a1[i] = *(const short8*)(Ap + ((wm + 64 + i * 16 + l15) << 6) + segc);
    if (h3s) {
      async_ld16(Pb + aG[1] + stA, dA + 8192 + tid * 16);
      async_ld16(Wb + bG[1] + stB, dB + 8192 + tid * 16);
      adv();
    }
    __builtin_amdgcn_s_barrier();
    asm volatile("s_waitcnt lgkmcnt(0)" ::: "memory");
    __builtin_amdgcn_sched_barrier(0);
    __builtin_amdgcn_s_setprio(1);
    #pragma unroll
    for (int i = 0; i < 4; ++i)
      #pragma unroll
      for (int j = 0; j < 4; ++j)
        acc[4 + i][j] = __builtin_amdgcn_mfma_f32_16x16x32_bf16(a1[i], b[j], acc[4 + i][j], 0, 0, 0);
    __builtin_amdgcn_s_setprio(0);
    // Boundary: wait loads of step t+1 (issued 2 steps ago); keep t+2,t+3 in flight.
    if (h3s)                asm volatile("s_waitcnt vmcnt(8)" ::: "memory");
    else if (h2s)           asm volatile("s_waitcnt vmcnt(4)" ::: "memory");
    else if (t + 1 < steps) asm volatile("s_waitcnt vmcnt(0)" ::: "memory");
    __builtin_amdgcn_sched_barrier(0);
    __builtin_amdgcn_s_barrier();
  }

  // Full drain before epilogue (hardening: nothing may leak past kernel end).
  asm volatile("s_waitcnt vmcnt(0) lgkmcnt(0)" ::: "memory");
  __builtin_amdgcn_s_barrier();

  // Epilogue: C/D layout col=lane&15, row=quad*4+reg. Raw bf16 partials.
  #pragma unroll
  for (int j = 0; j < 4; ++j) {
    const int o = n0 + wn + j * 16 + l15;
    #pragma unroll
    for (int i = 0; i < 8; ++i) {
      #pragma unroll
      for (int r = 0; r < 4; ++r) {
        int m = m0 + wm + i * 16 + quad * 4 + r;
        partOut[(size_t)m * COUT + o] = f2bf(acc[i][j][r]);
      }
    }
  }
}

// ---------------------------------------------------------------------------
// reduce1: sum 3 bf16 partial slices + bias, relu, cast bf16, scatter into
// padded P2 layout [t][6][16][16][1024] (interior only; halo pre-zeroed).
// ---------------------------------------------------------------------------
__global__ void reduce_conv1(const unsigned short* __restrict__ part,
                             const float* __restrict__ bias,
                             unsigned short* __restrict__ P2) {
  const int idx = blockIdx.x * 256 + threadIdx.x;
  const int m  = idx >> 8;
  const int o4 = (idx & 255) * 4;
  const size_t ss = (size_t)M_PAD * 1024;
  const size_t base = (size_t)m * 1024 + o4;
  ushort4v p0 = *(const ushort4v*)(part + base);
  ushort4v p1 = *(const ushort4v*)(part + ss + base);
  ushort4v p2 = *(const ushort4v*)(part + 2 * ss + base);
  ushort4v out;
  #pragma unroll
  for (int k = 0; k < 4; ++k) {
    float v = bf2f(p0[k]) + bf2f(p1[k]) + bf2f(p2[k]) + bias[o4 + k];
    out[k] = f2bf(v > 0.f ? v : 0.f);
  }
  int t = m / 784;  int r2 = m - t * 784;
  int d = r2 / 196; int r3 = r2 - d * 196;
  int h = r3 / 14;  int w = r3 - h * 14;
  size_t didx = (size_t)(((t * 6 + d + 1) * 16 + (h + 1)) * 16 + (w + 1)) * 1024 + o4;
  *(ushort4v*)(P2 + didx) = out;
}

// ---------------------------------------------------------------------------
// reduce2: sum 5 bf16 partial slices + bias, relu, cast bf16 -> h2 [6272][512].
// ---------------------------------------------------------------------------
__global__ void reduce_conv2(const unsigned short* __restrict__ part,
                             const float* __restrict__ bias,
                             unsigned short* __restrict__ h2) {
  const int idx = blockIdx.x * 256 + threadIdx.x;
  const int m  = idx >> 7;
  const int o4 = (idx & 127) * 4;
  const size_t base = (size_t)m * 512 + o4;
  const size_t ss = (size_t)M_PAD * 512;
  float acc[4];
  #pragma unroll
  for (int k = 0; k < 4; ++k) acc[k] = bias[o4 + k];
  #pragma unroll
  for (int s = 0; s < 5; ++s) {
    ushort4v p = *(const ushort4v*)(part + (size_t)s * ss + base);
    #pragma unroll
    for (int k = 0; k < 4; ++k) acc[k] += bf2f(p[k]);
  }
  ushort4v out;
  #pragma unroll
  for (int k = 0; k < 4; ++k) out[k] = f2bf(acc[k] > 0.f ? acc[k] : 0.f);
  *(ushort4v*)(h2 + base) = out;
}

// ---------------------------------------------------------------------------
// Max-pool, two-stage. h2 bf16 >= 0 -> bit pattern monotone -> max raw ushorts.
// ---------------------------------------------------------------------------
__global__ void pool1(const unsigned short* __restrict__ h2,
                      unsigned short* __restrict__ partial) {
  const int t = blockIdx.x / 28, ch = blockIdx.x % 28, o = threadIdx.x;
  const unsigned short* src = h2 + ((size_t)t * 784 + ch * 28) * 512 + o;
  unsigned short m = 0;
  #pragma unroll 4
  for (int i = 0; i < 28; ++i) { unsigned short v = src[(size_t)i * 512]; m = v > m ? v : m; }
  partial[((size_t)t * 28 + ch) * 512 + o] = m;
}

__global__ void pool2(const unsigned short* __restrict__ partial, float* __restrict__ pooled) {
  const int t = blockIdx.x, o = threadIdx.x;
  const unsigned short* src = partial + (size_t)t * 28 * 512 + o;
  unsigned short m = 0;
  #pragma unroll 4
  for (int i = 0; i < 28; ++i) { unsigned short v = src[(size_t)i * 512]; m = v > m ? v : m; }
  pooled[t * 512 + o] = bf2f(m);
}

// ---------------------------------------------------------------------------
// Tiny MLP, fp32. Block per t, 512 threads.
// ---------------------------------------------------------------------------
__global__ void mlp_kernel(const float* __restrict__ pooled,
                           const float* __restrict__ w1, const float* __restrict__ b1,
                           const float* __restrict__ w2, const float* __restrict__ b2,
                           const float* __restrict__ w3, const float* __restrict__ b3,
                           float* __restrict__ out) {
  const int t = blockIdx.x, j = threadIdx.x;
  __shared__ float xa[512], xb[512];
  xa[j] = pooled[t * 512 + j];
  __syncthreads();
  {
    const float4* wr = (const float4*)(w1 + (size_t)j * 512);
    float s = b1[j];
    #pragma unroll 4
    for (int k = 0; k < 128; ++k) {
      float4 wv = wr[k];
      s += wv.x * xa[4*k] + wv.y * xa[4*k+1] + wv.z * xa[4*k+2] + wv.w * xa[4*k+3];
    }
    xb[j] = fmaxf(s, 0.f);
  }
  __syncthreads();
  {
    const float4* wr = (const float4*)(w2 + (size_t)j * 512);
    float s = b2[j];
    #pragma unroll 4
    for (int k = 0; k < 128; ++k) {
      float4 wv = wr[k];
      s += wv.x * xb[4*k] + wv.y * xb[4*k+1] + wv.z * xb[4*k+2] + wv.w * xb[4*k+3];
    }
    xa[j] = fmaxf(s, 0.f);
  }
  __syncthreads();
  if (j < 128) {
    const float4* wr = (const float4*)(w3 + (size_t)j * 512);
    float s = b3[j];
    #pragma unroll 4
    for (int k = 0; k < 128; ++k) {
      float4 wv = wr[k];
      s += wv.x * xa[4*k] + wv.y * xa[4*k+1] + wv.z * xa[4*k+2] + wv.w * xa[4*k+3];
    }
    out[t * 128 + j] = fmaxf(s, 0.f);
  }
}

// ---------------------------------------------------------------------------
// Host schedule: per block (m-tile x2, n-tile, K-slice z, tap range).
// conv1: ns = nv/9 -> every block exactly 9 valid taps (uniform, 288 steps).
// conv2: ns = 5 (27 taps) or 4 (18 taps).  Grid <= 256 at 1 block/CU;
// XCD-grouped interleave (block g -> XCD g%8 contiguous chunk).
// ---------------------------------------------------------------------------
static int build_sched(bool conv1, unsigned int* out) {
  const int nt = conv1 ? 4 : 2;
  unsigned int L[256];
  int cnt = 0;
  for (int n = 0; n < nt; ++n) {
    for (int x2 = 0; x2 < 25; ++x2) {
      const int m0 = x2 * 256;
      bool kdv[3] = {false, false, false};
      const int cA = m0 / 196;
      int cB = (m0 + 255) / 196; if (cB > 31) cB = 31;
      for (int c = cA; c <= cB; ++c) {
        int t = c >> 2, d = c & 3;
        for (int kd = 0; kd < 3; ++kd) {
          int s = d + kd;
          bool ok = (s >= 1 && s <= 4);
          if (conv1) ok = ok && (s >= 5 - t);
          kdv[kd] = kdv[kd] || ok;
        }
      }
      int vt[27], nv = 0;
      for (int tp = 0; tp < 27; ++tp) if (kdv[tp / 9]) vt[nv++] = tp;
      if (!nv) continue;
      const int ns = conv1 ? (nv / 9) : ((nv == 27) ? 5 : 4);
      for (int s = 0; s < ns; ++s) {
        int b0 = nv * s / ns, b1 = nv * (s + 1) / ns;
        int tp0 = vt[b0], tp1 = vt[b1 - 1] + 1;
        L[cnt++] = (unsigned int)(x2 | (n << 5) | (s << 7) | (tp0 << 10) | (tp1 << 15));
      }
    }
  }
  const int q = cnt / 8, r = cnt % 8;
  int pos = 0;
  for (int b = 0; b < 8; ++b) {
    const int nb = q + (b < r ? 1 : 0);
    for (int j = 0; j < nb; ++j) out[j * 8 + b] = L[pos++];
  }
  return cnt;
}

// ---------------------------------------------------------------------------
// Workspace layout (bytes) — total 122,685,440:
//   P12 (P1/P2, 51 slots incl t=8 pad) @ 0         : 26,738,688
//   W1t                       @ 26,738,688         : 56,623,104  (dead after gemm1)
//     W2t  (aliases W1t)      @ 26,738,688         : 28,311,552  (built after gemm1)
//     h2                      @ 55,050,240         :  6,422,528
//     pooled                  @ 61,472,768         :     16,384
//     ppart                   @ 61,489,152         :    229,376
//   part                      @ 83,361,792         : 39,321,600  (conv1 3x6400x1024,
//                                                    conv2 5x6400x512 = 32,768,000)
//   sched1 / sched2           @ 122,683,392 / 122,684,416 : 1,024 each
// ---------------------------------------------------------------------------
extern "C" void kernel_launch(void* const* d_in, const int* in_sizes, int n_in,
                              void* d_out, int out_size, void* d_ws, size_t ws_size,
                              hipStream_t stream) {
  const float* videos = (const float*)d_in[0];
  const float* c1w = (const float*)d_in[1];
  const float* c1b = (const float*)d_in[2];
  const float* c2w = (const float*)d_in[3];
  const float* c2b = (const float*)d_in[4];
  const float* l1w = (const float*)d_in[5];
  const float* l1b = (const float*)d_in[6];
  const float* l2w = (const float*)d_in[7];
  const float* l2b = (const float*)d_in[8];
  const float* l3w = (const float*)d_in[9];
  const float* l3b = (const float*)d_in[10];

  char* ws = (char*)d_ws;
  unsigned short* P12   = (unsigned short*)(ws);
  unsigned short* W1t   = (unsigned short*)(ws + 26738688);
  unsigned short* W2t   = (unsigned short*)(ws + 26738688);   // aliases W1t
  unsigned short* h2    = (unsigned short*)(ws + 55050240);
  float*          pooled= (float*)(ws + 61472768);
  unsigned short* ppart = (unsigned short*)(ws + 61489152);
  unsigned short* part  = (unsigned short*)(ws + 83361792);
  unsigned int* dsched1 = (unsigned int*)(ws + 122683392);
  unsigned int* dsched2 = (unsigned int*)(ws + 122684416);
  float* out = (float*)d_out;

  // Host scheds: static so captured memcpy sources persist across graph replays.
  static unsigned int s1h[256], s2h[256];
  const int n1 = build_sched(true,  s1h);   // 228 blocks, all 9-tap uniform
  const int n2 = build_sched(false, s2h);   // 248 blocks
  hipMemcpyAsync(dsched1, s1h, sizeof(s1h), hipMemcpyHostToDevice, stream);
  hipMemcpyAsync(dsched2, s2h, sizeof(s2h), hipMemcpyHostToDevice, stream);

  // Zero padded activation buffer (halo + unused windows + t=8 pad slots).
  hipMemsetAsync(ws, 0, 26738688, stream);
  // Zero conv1 partials (empty m-tiles + unused slices).
  hipMemsetAsync(part, 0, 39321600, stream);

  wtrans<<<4096, 256, 0, stream>>>(c1w, W1t, 1024 * 1024);
  build_P1<<<dim3(8, 16), 256, 0, stream>>>(videos, P12);

  conv_gemm<1024, true ><<<n1, 512, 0, stream>>>(P12, W1t, dsched1, part);

  // W2t overwrites W1t — only after conv_gemm1 is done (stream order).
  wtrans<<<2048, 256, 0, stream>>>(c2w, W2t, 512 * 1024);
  reduce_conv1<<<6272, 256, 0, stream>>>(part, c1b, P12);
  // conv2: x2=24 blocks have 4 slices; zero z=4 rows 6144.. (after reduce1!).
  hipMemsetAsync((char*)part + 32505856, 0, 262144, stream);

  conv_gemm<512, false><<<n2, 512, 0, stream>>>(P12, W2t, dsched2, part);
  reduce_conv2<<<3136, 256, 0, stream>>>(part, c2b, h2);

  pool1<<<224, 512, 0, stream>>>(h2, ppart);
  pool2<<<8, 512, 0, stream>>>(ppart, pooled);
  mlp_kernel<<<8, 512, 0, stream>>>(pooled, l1w, l1b, l2w, l2b, l3w, l3b, out);
}

// Round 6
// 761.963 us; speedup vs baseline: 1.2033x; 1.0698x over previous
//
#include <hip/hip_runtime.h>

typedef __attribute__((ext_vector_type(8))) short short8;
typedef __attribute__((ext_vector_type(4))) float floatx4;
typedef __attribute__((ext_vector_type(4))) unsigned short ushort4v;

#define DEV __device__ __forceinline__

constexpr int M_TOT = 6272;   // 8 * 784 real output positions
constexpr int M_PAD = 6400;   // padded to 25*256 (pad rows read zeroed P slots)

DEV void async_ld16(const void* g, void* l) {
  __builtin_amdgcn_global_load_lds(
      (const __attribute__((address_space(1))) unsigned int*)g,
      (__attribute__((address_space(3))) unsigned int*)l,
      16, 0, 0);
}

DEV unsigned short f2bf(float x) {
  union { float f; unsigned int u; } v; v.f = x;
  unsigned int u = v.u;
  u += 0x7FFFu + ((u >> 16) & 1u);   // round-to-nearest-even
  return (unsigned short)(u >> 16);
}

DEV float bf2f(unsigned short s) {
  union { unsigned int u; float f; } v; v.u = ((unsigned int)s) << 16;
  return v.f;
}

// ---------------------------------------------------------------------------
// Weight transform: conv_w fp32 [O][C][3][3][3] -> bf16 [tap][o][c]  (B^T).
// ---------------------------------------------------------------------------
__global__ void wtrans(const float* __restrict__ w, unsigned short* __restrict__ wt,
                       int total /* = O*C, multiple of 256 */) {
  __shared__ unsigned short l[256 * 27];
  const int tid  = threadIdx.x;
  const int base = blockIdx.x * 256;
  #pragma unroll 1
  for (int j = tid; j < 256 * 27; j += 256)
    l[j] = f2bf(w[(size_t)base * 27 + j]);
  __syncthreads();
  #pragma unroll 1
  for (int tap = 0; tap < 27; ++tap)
    wt[(size_t)tap * total + base + tid] = l[tid * 27 + tap];
}

// ---------------------------------------------------------------------------
// Build P1: videos fp32 [8][1024][14][14] -> P1 bf16 [t=8][s=6][16][16][1024]
// P1[t][s][h+1][w+1][c] = videos[t-5+s][c][h][w] for s in 1..4 (else zero).
// ---------------------------------------------------------------------------
__global__ void build_P1(const float* __restrict__ videos, unsigned short* __restrict__ P1) {
  const int f  = blockIdx.x;
  const int c0 = blockIdx.y * 64;
  const int tid = threadIdx.x;
  __shared__ unsigned short tile[64][196];

  #pragma unroll 1
  for (int it = 0; it < 49; ++it) {       // 49*256 = 64*196 exactly
    int idx = it * 256 + tid;
    int c = idx / 196, r = idx - c * 196;
    tile[c][r] = f2bf(videos[(size_t)(f * 1024 + c0 + c) * 196 + r]);
  }
  __syncthreads();

  const int c   = tid & 63;
  const int hwq = tid >> 6;
  #pragma unroll 1
  for (int s = 1; s <= 4; ++s) {
    int t = f + 5 - s;
    if (t > 7) continue;
    unsigned short* dst = P1 + (size_t)(t * 6 + s) * 256 * 1024 + (size_t)c0;
    #pragma unroll 1
    for (int it = 0; it < 49; ++it) {
      int hw = it * 4 + hwq;
      int h = hw / 14, w = hw - h * 14;
      dst[(size_t)((h + 1) * 16 + (w + 1)) * 1024 + c] = tile[c][hw];
    }
  }
}

// ---------------------------------------------------------------------------
// R10: R8's verified two-phase skeleton (explicit lgkmcnt(0)+sched_barrier
// before each 16-MFMA cluster, clamped prologue, final drain) with the 4
// mid-step s_barriers removed — ONE boundary barrier per step (the only one
// the 4-slot protocol needs).  Waves free-run inside a step, so one wave's
// ds_reads overlap another's MFMAs (R8 serialized them: 2568 cyc/step vs
// max-pipe ~1300).
//
// Slot protocol (unchanged from R8, re-verified):
//  - reads of slot t&3: its loads retired by the vmcnt at step t-1's
//    boundary (all waves), barrier crossed.
//  - staging target (t+3)&3 == (t-1)&3: every wave's reads of that slot
//    were retired by its own phase-B lgkmcnt(0) BEFORE it crossed step
//    t-1's boundary barrier; staging is issued after crossing.
//  - boundary vmcnt(8) retires exactly step t+1's 4 loads (issued 2 steps
//    earlier); 8 loads (t+2, t+3) stay in flight.
//
// M padded to 6400: no tail blocks; all conv1 blocks exactly 9 taps (288
// steps) -> perfect per-CU balance at 1 block/CU.  Pad rows read zeroed P
// slots (t=8) -> contribute exact 0; pad part rows never read by reducers.
//
// LDS k-swizzle (64-B rows, 4 segs of 16 B): LDS(row,seg) holds global
// chunk seg ^ ((row>>1)&3); read seg = quad ^ ((l15>>1)&3).  8 consecutive
// lanes of a b128 cover all 32 banks exactly once -> conflict-free.
//
// A: padded input P [t=0..8][6][16][16][1024] bf16; B: Wt [27][COUT][1024].
// sched entry: x2:5 | n:2 | z:3 | tap0:5 | tap1:5
// ---------------------------------------------------------------------------
template <int COUT, bool TCOND>
__global__ __launch_bounds__(512, 2) void conv_gemm(
    const unsigned short* __restrict__ P,
    const unsigned short* __restrict__ Wt,
    const unsigned int* __restrict__ sched,
    unsigned short* __restrict__ part)
{
  constexpr int CIN = 1024;
  __shared__ short lA[4][8192];   // 4 slots x 16 KiB  (256 rows x 32 k)
  __shared__ short lB[4][8192];
  const int tid  = threadIdx.x;
  const int wave = tid >> 6;
  const int lane = tid & 63;

  const unsigned int e = sched[blockIdx.x];
  const int x2   = e & 31;
  const int nidx = (e >> 5) & 3;
  const int zs   = (e >> 7) & 7;
  const int tap0 = (e >> 10) & 31;
  const int tap1 = (e >> 15) & 31;
  const int m0 = x2 * 256;
  const int n0 = nidx * 256;
  unsigned short* partOut = part + (size_t)zs * M_PAD * COUT;

  // Tile-level depth-tap validity over spanned REAL (t,d) cells (pad excluded).
  bool kdv[3] = {false, false, false};
  {
    const int cA = m0 / 196;
    int cB = (m0 + 255) / 196; if (cB > 31) cB = 31;
    for (int c = cA; c <= cB; ++c) {
      int t = c >> 2, d = c & 3;
      #pragma unroll
      for (int kd = 0; kd < 3; ++kd) {
        int s = d + kd;
        bool ok = (s >= 1) && (s <= 4);
        if (TCOND) ok = ok && (s >= 5 - t);
        kdv[kd] = kdv[kd] || ok;
      }
    }
  }

  // Staging geometry: thread covers (row = tid>>2 within 128-row half,
  // seg = tid&3); global source pre-swizzled: chunk (tid&3) ^ ((row>>1)&3).
  const int arow = tid >> 2;
  const int aswz = (((tid & 3) ^ ((arow >> 1) & 3)) << 4);
  int aG[2], bG[2];
  #pragma unroll
  for (int q = 0; q < 2; ++q) {
    int m = m0 + q * 128 + arow;
    int t = m / 784;  int r2 = m - t * 784;
    int d = r2 / 196; int r3 = r2 - d * 196;
    int h = r3 / 14;  int w = r3 - h * 14;
    aG[q] = ((((t * 6 + d) * 16 + h) * 16 + w) * CIN) * 2 + aswz;
    bG[q] = (n0 + q * 128 + arow) * (CIN * 2) + aswz;
  }

  // Step stream: 32 K-steps per valid tap.
  int nvt = 0;
  for (int tp = tap0; tp < tap1; ++tp) if (kdv[tp / 9]) ++nvt;
  const int steps = nvt * 32;
  int tap_s = tap0;
  while (tap_s < tap1 && !kdv[tap_s / 9]) ++tap_s;
  int c_s = 0;
  int stA = 0, stB = 0;
  auto setBases = [&]() {
    const int kd = tap_s / 9, rm = tap_s - kd * 9;
    const int kh = rm / 3, kw = rm - kh * 3;
    stA = ((((kd * 16) + kh) * 16 + kw) * CIN) * 2 + c_s * 2;
    stB = tap_s * (COUT * CIN * 2) + c_s * 2;
  };
  auto adv = [&]() {
    c_s += 32;
    if (c_s == CIN) { c_s = 0; do { ++tap_s; } while (tap_s < tap1 && !kdv[tap_s / 9]); }
  };

  const char* Pb = (const char*)P;
  const char* Wb = (const char*)Wt;
  char* lAc = (char*)&lA[0][0];
  char* lBc = (char*)&lB[0][0];

  // Prologue: stage steps 0..min(steps,3)-1 into slots 0.., counted wait on
  // step 0 only.
  const int nst = steps < 3 ? steps : 3;
  #pragma unroll 1
  for (int s = 0; s < nst; ++s) {
    setBases();
    char* dA = lAc + s * 16384;
    char* dB = lBc + s * 16384;
    async_ld16(Pb + aG[0] + stA, dA + tid * 16);
    async_ld16(Wb + bG[0] + stB, dB + tid * 16);
    async_ld16(Pb + aG[1] + stA, dA + 8192 + tid * 16);
    async_ld16(Wb + bG[1] + stB, dB + 8192 + tid * 16);
    adv();
  }
  if (nst >= 3)      asm volatile("s_waitcnt vmcnt(8)" ::: "memory");
  else if (nst == 2) asm volatile("s_waitcnt vmcnt(4)" ::: "memory");
  else               asm volatile("s_waitcnt vmcnt(0)" ::: "memory");
  __builtin_amdgcn_s_barrier();
  __builtin_amdgcn_sched_barrier(0);

  const int wm   = (wave >> 2) * 128;
  const int wn   = (wave & 3) * 64;
  const int quad = lane >> 4;
  const int l15  = lane & 15;
  const int segc = ((quad ^ ((l15 >> 1) & 3)) << 4);

  floatx4 acc[8][4];
  const floatx4 zero4 = {0.f, 0.f, 0.f, 0.f};
  #pragma unroll
  for (int i = 0; i < 8; ++i)
    #pragma unroll
    for (int j = 0; j < 4; ++j) acc[i][j] = zero4;

  #pragma unroll 1
  for (int t = 0; t < steps; ++t) {
    const char* Ap = lAc + (t & 3) * 16384;
    const char* Bp = lBc + (t & 3) * 16384;
    const bool h3s = (t + 3 < steps);
    const bool h2s = (t + 2 < steps);
    char* dA = lAc + ((t + 3) & 3) * 16384;
    char* dB = lBc + ((t + 3) & 3) * 16384;
    if (h3s) setBases();

    // ---------------- phase A: B-frags + rows wm..wm+63 ----------------
    short8 b[4], a0[4];
    #pragma unroll
    for (int j = 0; j < 4; ++j)
      b[j] = *(const short8*)(Bp + ((wn + j * 16 + l15) << 6) + segc);
    #pragma unroll
    for (int i = 0; i < 4; ++i)
      a0[i] = *(const short8*)(Ap + ((wm + i * 16 + l15) << 6) + segc);
    if (h3s) {
      async_ld16(Pb + aG[0] + stA, dA + tid * 16);
      async_ld16(Wb + bG[0] + stB, dB + tid * 16);
    }
    asm volatile("s_waitcnt lgkmcnt(0)" ::: "memory");
    __builtin_amdgcn_sched_barrier(0);
    __builtin_amdgcn_s_setprio(1);
    #pragma unroll
    for (int i = 0; i < 4; ++i)
      #pragma unroll
      for (int j = 0; j < 4; ++j)
        acc[i][j] = __builtin_amdgcn_mfma_f32_16x16x32_bf16(a0[i], b[j], acc[i][j], 0, 0, 0);
    __builtin_amdgcn_s_setprio(0);

    // ---------------- phase B: rows wm+64..wm+127 ----------------
    short8 a1[4];
    #pragma unroll
    for (int i = 0; i < 4; ++i)
      a1[i] = *(const short8*)(Ap + ((wm + 64 + i * 16 + l15) << 6) + segc);
    if (h3s) {
      async_ld16(Pb + aG[1] + stA, dA + 8192 + tid * 16);
      async_ld16(Wb + bG[1] + stB, dB + 8192 + tid * 16);
      adv();
    }
    asm volatile("s_waitcnt lgkmcnt(0)" ::: "memory");
    __builtin_amdgcn_sched_barrier(0);
    __builtin_amdgcn_s_setprio(1);
    #pragma unroll
    for (int i = 0; i < 4; ++i)
      #pragma unroll
      for (int j = 0; j < 4; ++j)
        acc[4 + i][j] = __builtin_amdgcn_mfma_f32_16x16x32_bf16(a1[i], b[j], acc[4 + i][j], 0, 0, 0);
    __builtin_amdgcn_s_setprio(0);

    // Boundary (slot protocol): retire step t+1's loads (issued 2 steps
    // ago); keep t+2, t+3 in flight.  ONE barrier per step.
    if (h3s)                asm volatile("s_waitcnt vmcnt(8)" ::: "memory");
    else if (h2s)           asm volatile("s_waitcnt vmcnt(4)" ::: "memory");
    else if (t + 1 < steps) asm volatile("s_waitcnt vmcnt(0)" ::: "memory");
    __builtin_amdgcn_sched_barrier(0);
    __builtin_amdgcn_s_barrier();
    __builtin_amdgcn_sched_barrier(0);
  }

  // Full drain before epilogue (nothing may leak past kernel end).
  asm volatile("s_waitcnt vmcnt(0) lgkmcnt(0)" ::: "memory");
  __builtin_amdgcn_s_barrier();

  // Epilogue: C/D layout col=lane&15, row=quad*4+reg. Raw bf16 partials.
  #pragma unroll
  for (int j = 0; j < 4; ++j) {
    const int o = n0 + wn + j * 16 + l15;
    #pragma unroll
    for (int i = 0; i < 8; ++i) {
      #pragma unroll
      for (int r = 0; r < 4; ++r) {
        int m = m0 + wm + i * 16 + quad * 4 + r;
        partOut[(size_t)m * COUT + o] = f2bf(acc[i][j][r]);
      }
    }
  }
}

// ---------------------------------------------------------------------------
// reduce1: sum 3 bf16 partial slices + bias, relu, cast bf16, scatter into
// padded P2 layout [t][6][16][16][1024] (interior only; halo pre-zeroed).
// ---------------------------------------------------------------------------
__global__ void reduce_conv1(const unsigned short* __restrict__ part,
                             const float* __restrict__ bias,
                             unsigned short* __restrict__ P2) {
  const int idx = blockIdx.x * 256 + threadIdx.x;
  const int m  = idx >> 8;
  const int o4 = (idx & 255) * 4;
  const size_t ss = (size_t)M_PAD * 1024;
  const size_t base = (size_t)m * 1024 + o4;
  ushort4v p0 = *(const ushort4v*)(part + base);
  ushort4v p1 = *(const ushort4v*)(part + ss + base);
  ushort4v p2 = *(const ushort4v*)(part + 2 * ss + base);
  ushort4v out;
  #pragma unroll
  for (int k = 0; k < 4; ++k) {
    float v = bf2f(p0[k]) + bf2f(p1[k]) + bf2f(p2[k]) + bias[o4 + k];
    out[k] = f2bf(v > 0.f ? v : 0.f);
  }
  int t = m / 784;  int r2 = m - t * 784;
  int d = r2 / 196; int r3 = r2 - d * 196;
  int h = r3 / 14;  int w = r3 - h * 14;
  size_t didx = (size_t)(((t * 6 + d + 1) * 16 + (h + 1)) * 16 + (w + 1)) * 1024 + o4;
  *(ushort4v*)(P2 + didx) = out;
}

// ---------------------------------------------------------------------------
// reduce2: sum 5 bf16 partial slices + bias, relu, cast bf16 -> h2 [6272][512].
// ---------------------------------------------------------------------------
__global__ void reduce_conv2(const unsigned short* __restrict__ part,
                             const float* __restrict__ bias,
                             unsigned short* __restrict__ h2) {
  const int idx = blockIdx.x * 256 + threadIdx.x;
  const int m  = idx >> 7;
  const int o4 = (idx & 127) * 4;
  const size_t base = (size_t)m * 512 + o4;
  const size_t ss = (size_t)M_PAD * 512;
  float acc[4];
  #pragma unroll
  for (int k = 0; k < 4; ++k) acc[k] = bias[o4 + k];
  #pragma unroll
  for (int s = 0; s < 5; ++s) {
    ushort4v p = *(const ushort4v*)(part + (size_t)s * ss + base);
    #pragma unroll
    for (int k = 0; k < 4; ++k) acc[k] += bf2f(p[k]);
  }
  ushort4v out;
  #pragma unroll
  for (int k = 0; k < 4; ++k) out[k] = f2bf(acc[k] > 0.f ? acc[k] : 0.f);
  *(ushort4v*)(h2 + base) = out;
}

// ---------------------------------------------------------------------------
// Max-pool, two-stage. h2 bf16 >= 0 -> bit pattern monotone -> max raw ushorts.
// ---------------------------------------------------------------------------
__global__ void pool1(const unsigned short* __restrict__ h2,
                      unsigned short* __restrict__ partial) {
  const int t = blockIdx.x / 28, ch = blockIdx.x % 28, o = threadIdx.x;
  const unsigned short* src = h2 + ((size_t)t * 784 + ch * 28) * 512 + o;
  unsigned short m = 0;
  #pragma unroll 4
  for (int i = 0; i < 28; ++i) { unsigned short v = src[(size_t)i * 512]; m = v > m ? v : m; }
  partial[((size_t)t * 28 + ch) * 512 + o] = m;
}

__global__ void pool2(const unsigned short* __restrict__ partial, float* __restrict__ pooled) {
  const int t = blockIdx.x, o = threadIdx.x;
  const unsigned short* src = partial + (size_t)t * 28 * 512 + o;
  unsigned short m = 0;
  #pragma unroll 4
  for (int i = 0; i < 28; ++i) { unsigned short v = src[(size_t)i * 512]; m = v > m ? v : m; }
  pooled[t * 512 + o] = bf2f(m);
}

// ---------------------------------------------------------------------------
// Tiny MLP, fp32. Block per t, 512 threads.
// ---------------------------------------------------------------------------
__global__ void mlp_kernel(const float* __restrict__ pooled,
                           const float* __restrict__ w1, const float* __restrict__ b1,
                           const float* __restrict__ w2, const float* __restrict__ b2,
                           const float* __restrict__ w3, const float* __restrict__ b3,
                           float* __restrict__ out) {
  const int t = blockIdx.x, j = threadIdx.x;
  __shared__ float xa[512], xb[512];
  xa[j] = pooled[t * 512 + j];
  __syncthreads();
  {
    const float4* wr = (const float4*)(w1 + (size_t)j * 512);
    float s = b1[j];
    #pragma unroll 4
    for (int k = 0; k < 128; ++k) {
      float4 wv = wr[k];
      s += wv.x * xa[4*k] + wv.y * xa[4*k+1] + wv.z * xa[4*k+2] + wv.w * xa[4*k+3];
    }
    xb[j] = fmaxf(s, 0.f);
  }
  __syncthreads();
  {
    const float4* wr = (const float4*)(w2 + (size_t)j * 512);
    float s = b2[j];
    #pragma unroll 4
    for (int k = 0; k < 128; ++k) {
      float4 wv = wr[k];
      s += wv.x * xb[4*k] + wv.y * xb[4*k+1] + wv.z * xb[4*k+2] + wv.w * xb[4*k+3];
    }
    xa[j] = fmaxf(s, 0.f);
  }
  __syncthreads();
  if (j < 128) {
    const float4* wr = (const float4*)(w3 + (size_t)j * 512);
    float s = b3[j];
    #pragma unroll 4
    for (int k = 0; k < 128; ++k) {
      float4 wv = wr[k];
      s += wv.x * xa[4*k] + wv.y * xa[4*k+1] + wv.z * xa[4*k+2] + wv.w * xa[4*k+3];
    }
    out[t * 128 + j] = fmaxf(s, 0.f);
  }
}

// ---------------------------------------------------------------------------
// Host schedule: per block (m-tile x2, n-tile, K-slice z, tap range).
// conv1: ns = nv/9 -> every block exactly 9 valid taps (uniform, 288 steps).
// conv2: ns = 5 (27 taps) or 4 (18 taps).  Grid <= 256 at 1 block/CU;
// XCD-grouped interleave (block g -> XCD g%8 contiguous chunk).
// ---------------------------------------------------------------------------
static int build_sched(bool conv1, unsigned int* out) {
  const int nt = conv1 ? 4 : 2;
  unsigned int L[256];
  int cnt = 0;
  for (int n = 0; n < nt; ++n) {
    for (int x2 = 0; x2 < 25; ++x2) {
      const int m0 = x2 * 256;
      bool kdv[3] = {false, false, false};
      const int cA = m0 / 196;
      int cB = (m0 + 255) / 196; if (cB > 31) cB = 31;
      for (int c = cA; c <= cB; ++c) {
        int t = c >> 2, d = c & 3;
        for (int kd = 0; kd < 3; ++kd) {
          int s = d + kd;
          bool ok = (s >= 1 && s <= 4);
          if (conv1) ok = ok && (s >= 5 - t);
          kdv[kd] = kdv[kd] || ok;
        }
      }
      int vt[27], nv = 0;
      for (int tp = 0; tp < 27; ++tp) if (kdv[tp / 9]) vt[nv++] = tp;
      if (!nv) continue;
      const int ns = conv1 ? (nv / 9) : ((nv == 27) ? 5 : 4);
      for (int s = 0; s < ns; ++s) {
        int b0 = nv * s / ns, b1 = nv * (s + 1) / ns;
        int tp0 = vt[b0], tp1 = vt[b1 - 1] + 1;
        L[cnt++] = (unsigned int)(x2 | (n << 5) | (s << 7) | (tp0 << 10) | (tp1 << 15));
      }
    }
  }
  const int q = cnt / 8, r = cnt % 8;
  int pos = 0;
  for (int b = 0; b < 8; ++b) {
    const int nb = q + (b < r ? 1 : 0);
    for (int j = 0; j < nb; ++j) out[j * 8 + b] = L[pos++];
  }
  return cnt;
}

// ---------------------------------------------------------------------------
// Workspace layout (bytes) — total 122,685,440:
//   P12 (P1/P2, 51 slots incl t=8 pad) @ 0         : 26,738,688
//   W1t                       @ 26,738,688         : 56,623,104  (dead after gemm1)
//     W2t  (aliases W1t)      @ 26,738,688         : 28,311,552  (built after gemm1)
//     h2                      @ 55,050,240         :  6,422,528
//     pooled                  @ 61,472,768         :     16,384
//     ppart                   @ 61,489,152         :    229,376
//   part                      @ 83,361,792         : 39,321,600  (conv1 3x6400x1024,
//                                                    conv2 5x6400x512 = 32,768,000)
//   sched1 / sched2           @ 122,683,392 / 122,684,416 : 1,024 each
// ---------------------------------------------------------------------------
extern "C" void kernel_launch(void* const* d_in, const int* in_sizes, int n_in,
                              void* d_out, int out_size, void* d_ws, size_t ws_size,
                              hipStream_t stream) {
  const float* videos = (const float*)d_in[0];
  const float* c1w = (const float*)d_in[1];
  const float* c1b = (const float*)d_in[2];
  const float* c2w = (const float*)d_in[3];
  const float* c2b = (const float*)d_in[4];
  const float* l1w = (const float*)d_in[5];
  const float* l1b = (const float*)d_in[6];
  const float* l2w = (const float*)d_in[7];
  const float* l2b = (const float*)d_in[8];
  const float* l3w = (const float*)d_in[9];
  const float* l3b = (const float*)d_in[10];

  char* ws = (char*)d_ws;
  unsigned short* P12   = (unsigned short*)(ws);
  unsigned short* W1t   = (unsigned short*)(ws + 26738688);
  unsigned short* W2t   = (unsigned short*)(ws + 26738688);   // aliases W1t
  unsigned short* h2    = (unsigned short*)(ws + 55050240);
  float*          pooled= (float*)(ws + 61472768);
  unsigned short* ppart = (unsigned short*)(ws + 61489152);
  unsigned short* part  = (unsigned short*)(ws + 83361792);
  unsigned int* dsched1 = (unsigned int*)(ws + 122683392);
  unsigned int* dsched2 = (unsigned int*)(ws + 122684416);
  float* out = (float*)d_out;

  // Host scheds: static so captured memcpy sources persist across graph replays.
  static unsigned int s1h[256], s2h[256];
  const int n1 = build_sched(true,  s1h);   // 228 blocks, all 9-tap uniform
  const int n2 = build_sched(false, s2h);   // 248 blocks
  hipMemcpyAsync(dsched1, s1h, sizeof(s1h), hipMemcpyHostToDevice, stream);
  hipMemcpyAsync(dsched2, s2h, sizeof(s2h), hipMemcpyHostToDevice, stream);

  // Zero padded activation buffer (halo + unused windows + t=8 pad slots).
  hipMemsetAsync(ws, 0, 26738688, stream);
  // Zero conv1 partials (empty m-tiles + unused slices).
  hipMemsetAsync(part, 0, 39321600, stream);

  wtrans<<<4096, 256, 0, stream>>>(c1w, W1t, 1024 * 1024);
  build_P1<<<dim3(8, 16), 256, 0, stream>>>(videos, P12);

  conv_gemm<1024, true ><<<n1, 512, 0, stream>>>(P12, W1t, dsched1, part);

  // W2t overwrites W1t — only after conv_gemm1 is done (stream order).
  wtrans<<<2048, 256, 0, stream>>>(c2w, W2t, 512 * 1024);
  reduce_conv1<<<6272, 256, 0, stream>>>(part, c1b, P12);
  // conv2: x2=24 blocks have 4 slices; zero z=4 rows 6144.. (after reduce1!).
  hipMemsetAsync((char*)part + 32505856, 0, 262144, stream);

  conv_gemm<512, false><<<n2, 512, 0, stream>>>(P12, W2t, dsched2, part);
  reduce_conv2<<<3136, 256, 0, stream>>>(part, c2b, h2);

  pool1<<<224, 512, 0, stream>>>(h2, ppart);
  pool2<<<8, 512, 0, stream>>>(ppart, pooled);
  mlp_kernel<<<8, 512, 0, stream>>>(pooled, l1w, l1b, l2w, l2b, l3w, l3b, out);
}

// Round 7
// 755.492 us; speedup vs baseline: 1.2136x; 1.0086x over previous
//
#include <hip/hip_runtime.h>

typedef __attribute__((ext_vector_type(8))) short short8;
typedef __attribute__((ext_vector_type(4))) int int4v;
typedef __attribute__((ext_vector_type(4))) float floatx4;
typedef __attribute__((ext_vector_type(4))) unsigned short ushort4v;

#define DEV __device__ __forceinline__

constexpr int M_TOT = 6272;   // 8 * 784 real output positions
constexpr int M_PAD = 6400;   // padded to 25*256 (pad rows read zeroed P slots)

DEV void async_ld16(const void* g, void* l) {
  __builtin_amdgcn_global_load_lds(
      (const __attribute__((address_space(1))) unsigned int*)g,
      (__attribute__((address_space(3))) unsigned int*)l,
      16, 0, 0);
}

DEV unsigned short f2bf(float x) {
  union { float f; unsigned int u; } v; v.f = x;
  unsigned int u = v.u;
  u += 0x7FFFu + ((u >> 16) & 1u);   // round-to-nearest-even
  return (unsigned short)(u >> 16);
}

DEV float bf2f(unsigned short s) {
  union { unsigned int u; float f; } v; v.u = ((unsigned int)s) << 16;
  return v.f;
}

// ---------------------------------------------------------------------------
// Weight transform: conv_w fp32 [O][C][3][3][3] -> bf16 [tap][o][c]  (B^T).
// ---------------------------------------------------------------------------
__global__ void wtrans(const float* __restrict__ w, unsigned short* __restrict__ wt,
                       int total /* = O*C, multiple of 256 */) {
  __shared__ unsigned short l[256 * 27];
  const int tid  = threadIdx.x;
  const int base = blockIdx.x * 256;
  #pragma unroll 1
  for (int j = tid; j < 256 * 27; j += 256)
    l[j] = f2bf(w[(size_t)base * 27 + j]);
  __syncthreads();
  #pragma unroll 1
  for (int tap = 0; tap < 27; ++tap)
    wt[(size_t)tap * total + base + tid] = l[tid * 27 + tap];
}

// ---------------------------------------------------------------------------
// Build P1: videos fp32 [8][1024][14][14] -> P1 bf16 [t=8][s=6][16][16][1024]
// P1[t][s][h+1][w+1][c] = videos[t-5+s][c][h][w] for s in 1..4 (else zero).
// ---------------------------------------------------------------------------
__global__ void build_P1(const float* __restrict__ videos, unsigned short* __restrict__ P1) {
  const int f  = blockIdx.x;
  const int c0 = blockIdx.y * 64;
  const int tid = threadIdx.x;
  __shared__ unsigned short tile[64][196];

  #pragma unroll 1
  for (int it = 0; it < 49; ++it) {       // 49*256 = 64*196 exactly
    int idx = it * 256 + tid;
    int c = idx / 196, r = idx - c * 196;
    tile[c][r] = f2bf(videos[(size_t)(f * 1024 + c0 + c) * 196 + r]);
  }
  __syncthreads();

  const int c   = tid & 63;
  const int hwq = tid >> 6;
  #pragma unroll 1
  for (int s = 1; s <= 4; ++s) {
    int t = f + 5 - s;
    if (t > 7) continue;
    unsigned short* dst = P1 + (size_t)(t * 6 + s) * 256 * 1024 + (size_t)c0;
    #pragma unroll 1
    for (int it = 0; it < 49; ++it) {
      int hw = it * 4 + hwq;
      int h = hw / 14, w = hw - h * 14;
      dst[(size_t)((h + 1) * 16 + (w + 1)) * 1024 + c] = tile[c][hw];
    }
  }
}

// Pinned-order LDS read (issue order = program order among volatile asm).
#define DSR(dst, addr, off) \
  asm volatile("ds_read_b128 %0, %1 offset:" #off : "=&v"(dst) : "v"(addr))
#define WAITL(n) \
  asm volatile("s_waitcnt lgkmcnt(" #n ")" ::: "memory"); \
  __builtin_amdgcn_sched_barrier(0)

// ---------------------------------------------------------------------------
// R11: counted-lgkm ladder on the R10 single-barrier quad-buffer pipeline.
// R10's lgkmcnt(0) full drain before each 16-MFMA cluster left ~900 cyc/step
// of intra-wave stall (step 2187 cyc vs ~1300 max-pipe).  DS ops retire in
// order, so with a PINNED issue order (inline-asm ds_read_b128, immediate
// offsets) we interleave exactly: issue b0..b3,a0..a7 (+4 staging
// global_load_lds — vmcnt, doesn't touch lgkm), then
//   lgkmcnt(7)->MFMA(i=0), lgkmcnt(6)->i=1, ... lgkmcnt(0)->i=7,
// each wait + sched_barrier(0) (rule 18).  Tail reads drain under MFMA.
// Boundary protocol (counted vmcnt(8), ONE s_barrier/step) unchanged from
// R10 (validated).  Slot protocol identical:
//  - reads of slot t&3 covered by step t-1 boundary vmcnt+barrier
//  - staging target (t+3)&3 == (t-1)&3 dead (ladder ends lgkmcnt(0))
//  - boundary vmcnt(8) retires exactly step t+1's 4 loads
//
// M padded to 6400: no tail blocks; conv1 blocks exactly 9 taps (288 steps).
// LDS k-swizzle: LDS(row,seg) holds chunk seg ^ ((row>>1)&3); read seg =
// quad ^ ((l15>>1)&3) -> conflict-free b128.
// A: P [t=0..8][6][16][16][1024] bf16; B: Wt [27][COUT][1024].
// sched entry: x2:5 | n:2 | z:3 | tap0:5 | tap1:5
// ---------------------------------------------------------------------------
template <int COUT, bool TCOND>
__global__ __launch_bounds__(512, 2) void conv_gemm(
    const unsigned short* __restrict__ P,
    const unsigned short* __restrict__ Wt,
    const unsigned int* __restrict__ sched,
    unsigned short* __restrict__ part)
{
  constexpr int CIN = 1024;
  __shared__ short lA[4][8192];   // 4 slots x 16 KiB  (256 rows x 32 k)
  __shared__ short lB[4][8192];
  const int tid  = threadIdx.x;
  const int wave = tid >> 6;
  const int lane = tid & 63;

  const unsigned int e = sched[blockIdx.x];
  const int x2   = e & 31;
  const int nidx = (e >> 5) & 3;
  const int zs   = (e >> 7) & 7;
  const int tap0 = (e >> 10) & 31;
  const int tap1 = (e >> 15) & 31;
  const int m0 = x2 * 256;
  const int n0 = nidx * 256;
  unsigned short* partOut = part + (size_t)zs * M_PAD * COUT;

  // Tile-level depth-tap validity over spanned REAL (t,d) cells (pad excluded).
  bool kdv[3] = {false, false, false};
  {
    const int cA = m0 / 196;
    int cB = (m0 + 255) / 196; if (cB > 31) cB = 31;
    for (int c = cA; c <= cB; ++c) {
      int t = c >> 2, d = c & 3;
      #pragma unroll
      for (int kd = 0; kd < 3; ++kd) {
        int s = d + kd;
        bool ok = (s >= 1) && (s <= 4);
        if (TCOND) ok = ok && (s >= 5 - t);
        kdv[kd] = kdv[kd] || ok;
      }
    }
  }

  // Staging geometry: thread covers (row = tid>>2 within 128-row half,
  // seg = tid&3); global source pre-swizzled: chunk (tid&3) ^ ((row>>1)&3).
  const int arow = tid >> 2;
  const int aswz = (((tid & 3) ^ ((arow >> 1) & 3)) << 4);
  int aG[2], bG[2];
  #pragma unroll
  for (int q = 0; q < 2; ++q) {
    int m = m0 + q * 128 + arow;
    int t = m / 784;  int r2 = m - t * 784;
    int d = r2 / 196; int r3 = r2 - d * 196;
    int h = r3 / 14;  int w = r3 - h * 14;
    aG[q] = ((((t * 6 + d) * 16 + h) * 16 + w) * CIN) * 2 + aswz;
    bG[q] = (n0 + q * 128 + arow) * (CIN * 2) + aswz;
  }

  // Step stream: 32 K-steps per valid tap.
  int nvt = 0;
  for (int tp = tap0; tp < tap1; ++tp) if (kdv[tp / 9]) ++nvt;
  const int steps = nvt * 32;
  int tap_s = tap0;
  while (tap_s < tap1 && !kdv[tap_s / 9]) ++tap_s;
  int c_s = 0;
  int stA = 0, stB = 0;
  auto setBases = [&]() {
    const int kd = tap_s / 9, rm = tap_s - kd * 9;
    const int kh = rm / 3, kw = rm - kh * 3;
    stA = ((((kd * 16) + kh) * 16 + kw) * CIN) * 2 + c_s * 2;
    stB = tap_s * (COUT * CIN * 2) + c_s * 2;
  };
  auto adv = [&]() {
    c_s += 32;
    if (c_s == CIN) { c_s = 0; do { ++tap_s; } while (tap_s < tap1 && !kdv[tap_s / 9]); }
  };

  const char* Pb = (const char*)P;
  const char* Wb = (const char*)Wt;
  char* lAc = (char*)&lA[0][0];
  char* lBc = (char*)&lB[0][0];
  // 32-bit LDS byte offsets for ds_read asm (addrspacecast strips aperture).
  const unsigned ldsA0 =
      (unsigned)(size_t)(__attribute__((address_space(3))) char*)lAc;
  const unsigned ldsB0 =
      (unsigned)(size_t)(__attribute__((address_space(3))) char*)lBc;

  // Prologue: stage steps 0..min(steps,3)-1 into slots 0.., counted wait on
  // step 0 only.
  const int nst = steps < 3 ? steps : 3;
  #pragma unroll 1
  for (int s = 0; s < nst; ++s) {
    setBases();
    char* dA = lAc + s * 16384;
    char* dB = lBc + s * 16384;
    async_ld16(Pb + aG[0] + stA, dA + tid * 16);
    async_ld16(Wb + bG[0] + stB, dB + tid * 16);
    async_ld16(Pb + aG[1] + stA, dA + 8192 + tid * 16);
    async_ld16(Wb + bG[1] + stB, dB + 8192 + tid * 16);
    adv();
  }
  if (nst >= 3)      asm volatile("s_waitcnt vmcnt(8)" ::: "memory");
  else if (nst == 2) asm volatile("s_waitcnt vmcnt(4)" ::: "memory");
  else               asm volatile("s_waitcnt vmcnt(0)" ::: "memory");
  __builtin_amdgcn_s_barrier();
  __builtin_amdgcn_sched_barrier(0);

  const int wm   = (wave >> 2) * 128;
  const int wn   = (wave & 3) * 64;
  const int quad = lane >> 4;
  const int l15  = lane & 15;
  const int segc = ((quad ^ ((l15 >> 1) & 3)) << 4);
  const unsigned rowA = ((unsigned)(wm + l15) << 6) + segc;   // + i*1024 imm
  const unsigned rowB = ((unsigned)(wn + l15) << 6) + segc;   // + j*1024 imm

  floatx4 acc[8][4];
  const floatx4 zero4 = {0.f, 0.f, 0.f, 0.f};
  #pragma unroll
  for (int i = 0; i < 8; ++i)
    #pragma unroll
    for (int j = 0; j < 4; ++j) acc[i][j] = zero4;

  #pragma unroll 1
  for (int t = 0; t < steps; ++t) {
    const unsigned slot = (unsigned)(t & 3) * 16384u;
    const unsigned aBase = ldsA0 + slot + rowA;
    const unsigned bBase = ldsB0 + slot + rowB;
    const bool h3s = (t + 3 < steps);
    const bool h2s = (t + 2 < steps);
    char* dA = lAc + ((t + 3) & 3) * 16384;
    char* dB = lBc + ((t + 3) & 3) * 16384;
    if (h3s) setBases();

    // Issue 12 ds_reads in PINNED order: b0..b3, a0..a7.
    int4v bv[4], av[8];
    DSR(bv[0], bBase, 0);
    DSR(bv[1], bBase, 1024);
    DSR(bv[2], bBase, 2048);
    DSR(bv[3], bBase, 3072);
    DSR(av[0], aBase, 0);
    DSR(av[1], aBase, 1024);
    DSR(av[2], aBase, 2048);
    DSR(av[3], aBase, 3072);
    DSR(av[4], aBase, 4096);
    DSR(av[5], aBase, 5120);
    DSR(av[6], aBase, 6144);
    DSR(av[7], aBase, 7168);

    // Stage step t+3 into the dead slot (t-1)&3 (vmcnt ops; lgkm unaffected).
    if (h3s) {
      async_ld16(Pb + aG[0] + stA, dA + tid * 16);
      async_ld16(Wb + bG[0] + stB, dB + tid * 16);
      async_ld16(Pb + aG[1] + stA, dA + 8192 + tid * 16);
      async_ld16(Wb + bG[1] + stB, dB + 8192 + tid * 16);
      adv();
    }

    // Counted-lgkm ladder: group i ready when (7-i) reads still outstanding.
    __builtin_amdgcn_s_setprio(1);
    short8 bs[4];
    WAITL(7);
    #pragma unroll
    for (int j = 0; j < 4; ++j) bs[j] = __builtin_bit_cast(short8, bv[j]);
    {
      short8 a = __builtin_bit_cast(short8, av[0]);
      #pragma unroll
      for (int j = 0; j < 4; ++j)
        acc[0][j] = __builtin_amdgcn_mfma_f32_16x16x32_bf16(a, bs[j], acc[0][j], 0, 0, 0);
    }
    WAITL(6);
    {
      short8 a = __builtin_bit_cast(short8, av[1]);
      #pragma unroll
      for (int j = 0; j < 4; ++j)
        acc[1][j] = __builtin_amdgcn_mfma_f32_16x16x32_bf16(a, bs[j], acc[1][j], 0, 0, 0);
    }
    WAITL(5);
    {
      short8 a = __builtin_bit_cast(short8, av[2]);
      #pragma unroll
      for (int j = 0; j < 4; ++j)
        acc[2][j] = __builtin_amdgcn_mfma_f32_16x16x32_bf16(a, bs[j], acc[2][j], 0, 0, 0);
    }
    WAITL(4);
    {
      short8 a = __builtin_bit_cast(short8, av[3]);
      #pragma unroll
      for (int j = 0; j < 4; ++j)
        acc[3][j] = __builtin_amdgcn_mfma_f32_16x16x32_bf16(a, bs[j], acc[3][j], 0, 0, 0);
    }
    WAITL(3);
    {
      short8 a = __builtin_bit_cast(short8, av[4]);
      #pragma unroll
      for (int j = 0; j < 4; ++j)
        acc[4][j] = __builtin_amdgcn_mfma_f32_16x16x32_bf16(a, bs[j], acc[4][j], 0, 0, 0);
    }
    WAITL(2);
    {
      short8 a = __builtin_bit_cast(short8, av[5]);
      #pragma unroll
      for (int j = 0; j < 4; ++j)
        acc[5][j] = __builtin_amdgcn_mfma_f32_16x16x32_bf16(a, bs[j], acc[5][j], 0, 0, 0);
    }
    WAITL(1);
    {
      short8 a = __builtin_bit_cast(short8, av[6]);
      #pragma unroll
      for (int j = 0; j < 4; ++j)
        acc[6][j] = __builtin_amdgcn_mfma_f32_16x16x32_bf16(a, bs[j], acc[6][j], 0, 0, 0);
    }
    WAITL(0);
    {
      short8 a = __builtin_bit_cast(short8, av[7]);
      #pragma unroll
      for (int j = 0; j < 4; ++j)
        acc[7][j] = __builtin_amdgcn_mfma_f32_16x16x32_bf16(a, bs[j], acc[7][j], 0, 0, 0);
    }
    __builtin_amdgcn_s_setprio(0);

    // Boundary (slot protocol): retire step t+1's loads (issued 2 steps
    // ago); keep t+2, t+3 in flight.  ONE barrier per step.
    if (h3s)                asm volatile("s_waitcnt vmcnt(8)" ::: "memory");
    else if (h2s)           asm volatile("s_waitcnt vmcnt(4)" ::: "memory");
    else if (t + 1 < steps) asm volatile("s_waitcnt vmcnt(0)" ::: "memory");
    __builtin_amdgcn_sched_barrier(0);
    __builtin_amdgcn_s_barrier();
    __builtin_amdgcn_sched_barrier(0);
  }

  // Full drain before epilogue (nothing may leak past kernel end).
  asm volatile("s_waitcnt vmcnt(0) lgkmcnt(0)" ::: "memory");
  __builtin_amdgcn_s_barrier();

  // Epilogue: C/D layout col=lane&15, row=quad*4+reg. Raw bf16 partials.
  #pragma unroll
  for (int j = 0; j < 4; ++j) {
    const int o = n0 + wn + j * 16 + l15;
    #pragma unroll
    for (int i = 0; i < 8; ++i) {
      #pragma unroll
      for (int r = 0; r < 4; ++r) {
        int m = m0 + wm + i * 16 + quad * 4 + r;
        partOut[(size_t)m * COUT + o] = f2bf(acc[i][j][r]);
      }
    }
  }
}

// ---------------------------------------------------------------------------
// reduce1: sum 3 bf16 partial slices + bias, relu, cast bf16, scatter into
// padded P2 layout [t][6][16][16][1024] (interior only; halo pre-zeroed).
// ---------------------------------------------------------------------------
__global__ void reduce_conv1(const unsigned short* __restrict__ part,
                             const float* __restrict__ bias,
                             unsigned short* __restrict__ P2) {
  const int idx = blockIdx.x * 256 + threadIdx.x;
  const int m  = idx >> 8;
  const int o4 = (idx & 255) * 4;
  const size_t ss = (size_t)M_PAD * 1024;
  const size_t base = (size_t)m * 1024 + o4;
  ushort4v p0 = *(const ushort4v*)(part + base);
  ushort4v p1 = *(const ushort4v*)(part + ss + base);
  ushort4v p2 = *(const ushort4v*)(part + 2 * ss + base);
  ushort4v out;
  #pragma unroll
  for (int k = 0; k < 4; ++k) {
    float v = bf2f(p0[k]) + bf2f(p1[k]) + bf2f(p2[k]) + bias[o4 + k];
    out[k] = f2bf(v > 0.f ? v : 0.f);
  }
  int t = m / 784;  int r2 = m - t * 784;
  int d = r2 / 196; int r3 = r2 - d * 196;
  int h = r3 / 14;  int w = r3 - h * 14;
  size_t didx = (size_t)(((t * 6 + d + 1) * 16 + (h + 1)) * 16 + (w + 1)) * 1024 + o4;
  *(ushort4v*)(P2 + didx) = out;
}

// ---------------------------------------------------------------------------
// reduce2: sum 5 bf16 partial slices + bias, relu, cast bf16 -> h2 [6272][512].
// ---------------------------------------------------------------------------
__global__ void reduce_conv2(const unsigned short* __restrict__ part,
                             const float* __restrict__ bias,
                             unsigned short* __restrict__ h2) {
  const int idx = blockIdx.x * 256 + threadIdx.x;
  const int m  = idx >> 7;
  const int o4 = (idx & 127) * 4;
  const size_t base = (size_t)m * 512 + o4;
  const size_t ss = (size_t)M_PAD * 512;
  float acc[4];
  #pragma unroll
  for (int k = 0; k < 4; ++k) acc[k] = bias[o4 + k];
  #pragma unroll
  for (int s = 0; s < 5; ++s) {
    ushort4v p = *(const ushort4v*)(part + (size_t)s * ss + base);
    #pragma unroll
    for (int k = 0; k < 4; ++k) acc[k] += bf2f(p[k]);
  }
  ushort4v out;
  #pragma unroll
  for (int k = 0; k < 4; ++k) out[k] = f2bf(acc[k] > 0.f ? acc[k] : 0.f);
  *(ushort4v*)(h2 + base) = out;
}

// ---------------------------------------------------------------------------
// Max-pool, two-stage. h2 bf16 >= 0 -> bit pattern monotone -> max raw ushorts.
// ---------------------------------------------------------------------------
__global__ void pool1(const unsigned short* __restrict__ h2,
                      unsigned short* __restrict__ partial) {
  const int t = blockIdx.x / 28, ch = blockIdx.x % 28, o = threadIdx.x;
  const unsigned short* src = h2 + ((size_t)t * 784 + ch * 28) * 512 + o;
  unsigned short m = 0;
  #pragma unroll 4
  for (int i = 0; i < 28; ++i) { unsigned short v = src[(size_t)i * 512]; m = v > m ? v : m; }
  partial[((size_t)t * 28 + ch) * 512 + o] = m;
}

__global__ void pool2(const unsigned short* __restrict__ partial, float* __restrict__ pooled) {
  const int t = blockIdx.x, o = threadIdx.x;
  const unsigned short* src = partial + (size_t)t * 28 * 512 + o;
  unsigned short m = 0;
  #pragma unroll 4
  for (int i = 0; i < 28; ++i) { unsigned short v = src[(size_t)i * 512]; m = v > m ? v : m; }
  pooled[t * 512 + o] = bf2f(m);
}

// ---------------------------------------------------------------------------
// Tiny MLP, fp32. Block per t, 512 threads.
// ---------------------------------------------------------------------------
__global__ void mlp_kernel(const float* __restrict__ pooled,
                           const float* __restrict__ w1, const float* __restrict__ b1,
                           const float* __restrict__ w2, const float* __restrict__ b2,
                           const float* __restrict__ w3, const float* __restrict__ b3,
                           float* __restrict__ out) {
  const int t = blockIdx.x, j = threadIdx.x;
  __shared__ float xa[512], xb[512];
  xa[j] = pooled[t * 512 + j];
  __syncthreads();
  {
    const float4* wr = (const float4*)(w1 + (size_t)j * 512);
    float s = b1[j];
    #pragma unroll 4
    for (int k = 0; k < 128; ++k) {
      float4 wv = wr[k];
      s += wv.x * xa[4*k] + wv.y * xa[4*k+1] + wv.z * xa[4*k+2] + wv.w * xa[4*k+3];
    }
    xb[j] = fmaxf(s, 0.f);
  }
  __syncthreads();
  {
    const float4* wr = (const float4*)(w2 + (size_t)j * 512);
    float s = b2[j];
    #pragma unroll 4
    for (int k = 0; k < 128; ++k) {
      float4 wv = wr[k];
      s += wv.x * xb[4*k] + wv.y * xb[4*k+1] + wv.z * xb[4*k+2] + wv.w * xb[4*k+3];
    }
    xa[j] = fmaxf(s, 0.f);
  }
  __syncthreads();
  if (j < 128) {
    const float4* wr = (const float4*)(w3 + (size_t)j * 512);
    float s = b3[j];
    #pragma unroll 4
    for (int k = 0; k < 128; ++k) {
      float4 wv = wr[k];
      s += wv.x * xa[4*k] + wv.y * xa[4*k+1] + wv.z * xa[4*k+2] + wv.w * xa[4*k+3];
    }
    out[t * 128 + j] = fmaxf(s, 0.f);
  }
}

// ---------------------------------------------------------------------------
// Host schedule: per block (m-tile x2, n-tile, K-slice z, tap range).
// conv1: ns = nv/9 -> every block exactly 9 valid taps (uniform, 288 steps).
// conv2: ns = 5 (27 taps) or 4 (18 taps).  Grid <= 256 at 1 block/CU;
// XCD-grouped interleave (block g -> XCD g%8 contiguous chunk).
// ---------------------------------------------------------------------------
static int build_sched(bool conv1, unsigned int* out) {
  const int nt = conv1 ? 4 : 2;
  unsigned int L[256];
  int cnt = 0;
  for (int n = 0; n < nt; ++n) {
    for (int x2 = 0; x2 < 25; ++x2) {
      const int m0 = x2 * 256;
      bool kdv[3] = {false, false, false};
      const int cA = m0 / 196;
      int cB = (m0 + 255) / 196; if (cB > 31) cB = 31;
      for (int c = cA; c <= cB; ++c) {
        int t = c >> 2, d = c & 3;
        for (int kd = 0; kd < 3; ++kd) {
          int s = d + kd;
          bool ok = (s >= 1 && s <= 4);
          if (conv1) ok = ok && (s >= 5 - t);
          kdv[kd] = kdv[kd] || ok;
        }
      }
      int vt[27], nv = 0;
      for (int tp = 0; tp < 27; ++tp) if (kdv[tp / 9]) vt[nv++] = tp;
      if (!nv) continue;
      const int ns = conv1 ? (nv / 9) : ((nv == 27) ? 5 : 4);
      for (int s = 0; s < ns; ++s) {
        int b0 = nv * s / ns, b1 = nv * (s + 1) / ns;
        int tp0 = vt[b0], tp1 = vt[b1 - 1] + 1;
        L[cnt++] = (unsigned int)(x2 | (n << 5) | (s << 7) | (tp0 << 10) | (tp1 << 15));
      }
    }
  }
  const int q = cnt / 8, r = cnt % 8;
  int pos = 0;
  for (int b = 0; b < 8; ++b) {
    const int nb = q + (b < r ? 1 : 0);
    for (int j = 0; j < nb; ++j) out[j * 8 + b] = L[pos++];
  }
  return cnt;
}

// ---------------------------------------------------------------------------
// Workspace layout (bytes) — total 122,685,440:
//   P12 (P1/P2, 51 slots incl t=8 pad) @ 0         : 26,738,688
//   W1t                       @ 26,738,688         : 56,623,104  (dead after gemm1)
//     W2t  (aliases W1t)      @ 26,738,688         : 28,311,552  (built after gemm1)
//     h2                      @ 55,050,240         :  6,422,528
//     pooled                  @ 61,472,768         :     16,384
//     ppart                   @ 61,489,152         :    229,376
//   part                      @ 83,361,792         : 39,321,600  (conv1 3x6400x1024,
//                                                    conv2 5x6400x512 = 32,768,000)
//   sched1 / sched2           @ 122,683,392 / 122,684,416 : 1,024 each
// ---------------------------------------------------------------------------
extern "C" void kernel_launch(void* const* d_in, const int* in_sizes, int n_in,
                              void* d_out, int out_size, void* d_ws, size_t ws_size,
                              hipStream_t stream) {
  const float* videos = (const float*)d_in[0];
  const float* c1w = (const float*)d_in[1];
  const float* c1b = (const float*)d_in[2];
  const float* c2w = (const float*)d_in[3];
  const float* c2b = (const float*)d_in[4];
  const float* l1w = (const float*)d_in[5];
  const float* l1b = (const float*)d_in[6];
  const float* l2w = (const float*)d_in[7];
  const float* l2b = (const float*)d_in[8];
  const float* l3w = (const float*)d_in[9];
  const float* l3b = (const float*)d_in[10];

  char* ws = (char*)d_ws;
  unsigned short* P12   = (unsigned short*)(ws);
  unsigned short* W1t   = (unsigned short*)(ws + 26738688);
  unsigned short* W2t   = (unsigned short*)(ws + 26738688);   // aliases W1t
  unsigned short* h2    = (unsigned short*)(ws + 55050240);
  float*          pooled= (float*)(ws + 61472768);
  unsigned short* ppart = (unsigned short*)(ws + 61489152);
  unsigned short* part  = (unsigned short*)(ws + 83361792);
  unsigned int* dsched1 = (unsigned int*)(ws + 122683392);
  unsigned int* dsched2 = (unsigned int*)(ws + 122684416);
  float* out = (float*)d_out;

  // Host scheds: static so captured memcpy sources persist across graph replays.
  static unsigned int s1h[256], s2h[256];
  const int n1 = build_sched(true,  s1h);   // 228 blocks, all 9-tap uniform
  const int n2 = build_sched(false, s2h);   // 248 blocks
  hipMemcpyAsync(dsched1, s1h, sizeof(s1h), hipMemcpyHostToDevice, stream);
  hipMemcpyAsync(dsched2, s2h, sizeof(s2h), hipMemcpyHostToDevice, stream);

  // Zero padded activation buffer (halo + unused windows + t=8 pad slots).
  hipMemsetAsync(ws, 0, 26738688, stream);
  // Zero conv1 partials (empty m-tiles + unused slices).
  hipMemsetAsync(part, 0, 39321600, stream);

  wtrans<<<4096, 256, 0, stream>>>(c1w, W1t, 1024 * 1024);
  build_P1<<<dim3(8, 16), 256, 0, stream>>>(videos, P12);

  conv_gemm<1024, true ><<<n1, 512, 0, stream>>>(P12, W1t, dsched1, part);

  // W2t overwrites W1t — only after conv_gemm1 is done (stream order).
  wtrans<<<2048, 256, 0, stream>>>(c2w, W2t, 512 * 1024);
  reduce_conv1<<<6272, 256, 0, stream>>>(part, c1b, P12);
  // conv2: x2=24 blocks have 4 slices; zero z=4 rows 6144.. (after reduce1!).
  hipMemsetAsync((char*)part + 32505856, 0, 262144, stream);

  conv_gemm<512, false><<<n2, 512, 0, stream>>>(P12, W2t, dsched2, part);
  reduce_conv2<<<3136, 256, 0, stream>>>(part, c2b, h2);

  pool1<<<224, 512, 0, stream>>>(h2, ppart);
  pool2<<<8, 512, 0, stream>>>(ppart, pooled);
  mlp_kernel<<<8, 512, 0, stream>>>(pooled, l1w, l1b, l2w, l2b, l3w, l3b, out);
}